// Round 1
// baseline (135.921 us; speedup 1.0000x reference)
//
#include <hip/hip_runtime.h>

typedef _Float16 f16;
typedef _Float16 f16x4 __attribute__((ext_vector_type(4)));
typedef _Float16 f16x8 __attribute__((ext_vector_type(8)));
typedef float    f32x16 __attribute__((ext_vector_type(16)));

#define MFMA(a, b, c) __builtin_amdgcn_mfma_f32_32x32x16_f16((a), (b), (c), 0, 0, 0)

static constexpr int Mg   = 16384;   // atoms per batch
static constexpr int Bg   = 2;       // batches
static constexpr int Dg   = 256;     // feature dim
static constexpr int Hg   = 8;       // heads
static constexpr int Cg   = 512;     // query blocks per batch (M/32)
static constexpr int Ntok = 2048;    // tokens
static constexpr float QSCALE = 0.17677669529663687f; // 1/sqrt(32)

static __device__ __forceinline__ f16x8 mk8(f16x4 a, f16x4 b) {
    f16x8 r;
    r[0] = a[0]; r[1] = a[1]; r[2] = a[2]; r[3] = a[3];
    r[4] = b[0]; r[5] = b[1]; r[6] = b[2]; r[7] = b[3];
    return r;
}
static __device__ __forceinline__ f16x4 ld4(const f16* p) {
    return *reinterpret_cast<const f16x4*>(p);
}

// ---------------------------------------------------------------------------
// k_wt: W[k][n] fp32 -> WT[w][n][k] fp16 for Wq,Wk,Wv,Wo
// ---------------------------------------------------------------------------
__global__ __launch_bounds__(256) void k_wt(const float* __restrict__ Wq,
                                            const float* __restrict__ Wk,
                                            const float* __restrict__ Wv,
                                            const float* __restrict__ Wo,
                                            f16* __restrict__ WT) {
    int idx = blockIdx.x * 256 + threadIdx.x;     // 0 .. 4*65536-1
    int w   = idx >> 16;
    int rem = idx & 65535;
    int k   = rem >> 8;
    int n   = rem & 255;
    const float* W = (w == 0) ? Wq : (w == 1) ? Wk : (w == 2) ? Wv : Wo;
    WT[w * 65536 + n * 256 + k] = (f16)W[k * 256 + n];
}

// ---------------------------------------------------------------------------
// k_qkv: [32768x256] fp32  x  WT (fp16, [n][k])  ->  Q (scaled), K row-major,
//        V transposed into VT[b][d][m].  BM=BN=128, BK=64, 4 waves.
// grid = (6, 256): x = {w*2 + ntile}, y = row tile
// ---------------------------------------------------------------------------
__global__ __launch_bounds__(256) void k_qkv(const float* __restrict__ A,
                                             const f16* __restrict__ WT,
                                             f16* __restrict__ Qo,
                                             f16* __restrict__ Ko,
                                             f16* __restrict__ VT) {
    __shared__ f16 As[128 * 68];
    __shared__ f16 Ws[128 * 68];

    const int tid  = threadIdx.x;
    const int wix  = blockIdx.x >> 1;           // 0=Q 1=K 2=V
    const int n0   = (blockIdx.x & 1) * 128;
    const int m0   = blockIdx.y * 128;
    const int lane = tid & 63;
    const int wid  = tid >> 6;
    const int wm   = wid >> 1, wn = wid & 1;
    const int l31  = lane & 31, hi = lane >> 5;
    const f16* Wb  = WT + wix * 65536;

    f32x16 acc[2][2];
#pragma unroll
    for (int mi = 0; mi < 2; ++mi)
#pragma unroll
        for (int ni = 0; ni < 2; ++ni)
#pragma unroll
            for (int e = 0; e < 16; ++e) acc[mi][ni][e] = 0.f;

    for (int k0 = 0; k0 < 256; k0 += 64) {
        // stage A tile 128x64 (fp32 -> fp16)
#pragma unroll
        for (int i = 0; i < 8; ++i) {
            int flat = i * 256 + tid;
            int r = flat >> 4, cc = (flat & 15) << 2;
            float4 v = *reinterpret_cast<const float4*>(A + (size_t)(m0 + r) * 256 + k0 + cc);
            f16x4 hq = { (f16)v.x, (f16)v.y, (f16)v.z, (f16)v.w };
            *reinterpret_cast<f16x4*>(&As[r * 68 + cc]) = hq;
        }
        // stage WT tile 128x64 (fp16)
#pragma unroll
        for (int i = 0; i < 4; ++i) {
            int flat = i * 256 + tid;
            int r = flat >> 3, cc = (flat & 7) << 3;
            const f16* src = Wb + (size_t)(n0 + r) * 256 + k0 + cc;
            f16x4 a0 = ld4(src);
            f16x4 a1 = ld4(src + 4);
            *reinterpret_cast<f16x4*>(&Ws[r * 68 + cc]) = a0;
            *reinterpret_cast<f16x4*>(&Ws[r * 68 + cc + 4]) = a1;
        }
        __syncthreads();

#pragma unroll
        for (int ks = 0; ks < 4; ++ks) {
            const int kl = ks * 16 + 4 * hi;
            f16x8 af[2], bf[2];
#pragma unroll
            for (int mi = 0; mi < 2; ++mi) {
                const f16* p = &As[(wm * 64 + mi * 32 + l31) * 68 + kl];
                af[mi] = mk8(ld4(p), ld4(p + 8));
            }
#pragma unroll
            for (int ni = 0; ni < 2; ++ni) {
                const f16* p = &Ws[(wn * 64 + ni * 32 + l31) * 68 + kl];
                bf[ni] = mk8(ld4(p), ld4(p + 8));
            }
#pragma unroll
            for (int mi = 0; mi < 2; ++mi)
#pragma unroll
                for (int ni = 0; ni < 2; ++ni)
                    acc[mi][ni] = MFMA(af[mi], bf[ni], acc[mi][ni]);
        }
        __syncthreads();
    }

    // epilogue
#pragma unroll
    for (int mi = 0; mi < 2; ++mi) {
#pragma unroll
        for (int ni = 0; ni < 2; ++ni) {
            const int gcol  = n0 + wn * 64 + ni * 32 + l31;
            const int mbase = m0 + wm * 64 + mi * 32 + 4 * hi;
            if (wix == 0) {
#pragma unroll
                for (int r = 0; r < 16; ++r) {
                    int grow = mbase + (r & 3) + 8 * (r >> 2);
                    Qo[(size_t)grow * 256 + gcol] = (f16)(acc[mi][ni][r] * QSCALE);
                }
            } else if (wix == 1) {
#pragma unroll
                for (int r = 0; r < 16; ++r) {
                    int grow = mbase + (r & 3) + 8 * (r >> 2);
                    Ko[(size_t)grow * 256 + gcol] = (f16)acc[mi][ni][r];
                }
            } else {
#pragma unroll
                for (int rq = 0; rq < 4; ++rq) {
                    f16x4 pv = { (f16)acc[mi][ni][rq * 4 + 0], (f16)acc[mi][ni][rq * 4 + 1],
                                 (f16)acc[mi][ni][rq * 4 + 2], (f16)acc[mi][ni][rq * 4 + 3] };
                    int mrow = mbase + 8 * rq;          // +j (0..3) are consecutive atoms
                    int bb = mrow >> 14, mm = mrow & 16383;
                    *reinterpret_cast<f16x4*>(VT + (size_t)bb * (256 * 16384) +
                                              (size_t)gcol * 16384 + mm) = pv;
                }
            }
        }
    }
}

// ---------------------------------------------------------------------------
// k_attn: one wave per (head, qblock, batch). grid = (8, 512, 2), block = 64.
// Swapped QK^T: mfma(K,Q) -> lane owns one q-row; softmax in-register; P feeds
// PV A-operand directly; V from transposed VT.
// ---------------------------------------------------------------------------
__global__ __launch_bounds__(64) void k_attn(const f16* __restrict__ Qo,
                                             const f16* __restrict__ Ko,
                                             const f16* __restrict__ VT,
                                             f16* __restrict__ AO) {
    const int h = blockIdx.x, c = blockIdx.y, b = blockIdx.z;
    const int lane = threadIdx.x;
    const int l31 = lane & 31, hi = lane >> 5;

    const int s0   = (32 * c - 48 > 0) ? (32 * c - 48) : 0;
    const int e0   = (32 * c + 80 < Mg) ? (32 * c + 80) : Mg;
    const int wlen = e0 - s0;

    // Q fragments (B-operand: n = q = lane&31)
    const f16* qp = Qo + ((size_t)b * Mg + 32 * c + l31) * 256 + h * 32;
    f16x8 qf0 = mk8(ld4(qp + 4 * hi), ld4(qp + 4 * hi + 8));
    f16x8 qf1 = mk8(ld4(qp + 16 + 4 * hi), ld4(qp + 16 + 4 * hi + 8));

    f32x16 p4[4];
#pragma unroll
    for (int t = 0; t < 4; ++t)
#pragma unroll
        for (int e = 0; e < 16; ++e) p4[t][e] = 0.f;

    // scores^T: C[key][q]
#pragma unroll
    for (int t = 0; t < 4; ++t) {
        int kr = s0 + 32 * t + l31;
        if (kr > Mg - 1) kr = Mg - 1;                 // masked later
        const f16* kp = Ko + ((size_t)b * Mg + kr) * 256 + h * 32;
        f16x8 kf0 = mk8(ld4(kp + 4 * hi), ld4(kp + 4 * hi + 8));
        f16x8 kf1 = mk8(ld4(kp + 16 + 4 * hi), ld4(kp + 16 + 4 * hi + 8));
        p4[t] = MFMA(kf0, qf0, p4[t]);
        p4[t] = MFMA(kf1, qf1, p4[t]);
    }

    // masked softmax over this lane's q-row (keys split across lane^32 pair)
    float mx = -3e38f;
#pragma unroll
    for (int t = 0; t < 4; ++t)
#pragma unroll
        for (int r = 0; r < 16; ++r) {
            int kk = 32 * t + (r & 3) + 8 * (r >> 2) + 4 * hi;
            if (kk < wlen) mx = fmaxf(mx, p4[t][r]);
        }
    mx = fmaxf(mx, __shfl_xor(mx, 32));

    float sum = 0.f;
#pragma unroll
    for (int t = 0; t < 4; ++t)
#pragma unroll
        for (int r = 0; r < 16; ++r) {
            int kk = 32 * t + (r & 3) + 8 * (r >> 2) + 4 * hi;
            float ev = (kk < wlen) ? __expf(p4[t][r] - mx) : 0.f;
            p4[t][r] = ev;
            sum += ev;
        }
    sum += __shfl_xor(sum, 32);
    const float inv = 1.f / sum;
#pragma unroll
    for (int t = 0; t < 4; ++t)
#pragma unroll
        for (int e = 0; e < 16; ++e) p4[t][e] *= inv;

    // PV: O = P·V, A = P (lane-local), B = V from VT
    f32x16 o;
#pragma unroll
    for (int e = 0; e < 16; ++e) o[e] = 0.f;

    const f16* vp = VT + ((size_t)b * 256 + h * 32 + l31) * Mg;
#pragma unroll
    for (int s = 0; s < 8; ++s) {
        f16x8 pa;
#pragma unroll
        for (int e = 0; e < 8; ++e) pa[e] = (f16)(p4[s >> 1][8 * (s & 1) + e]);
        int c0 = s0 + 16 * s + 4 * hi;
        int c1 = c0 + 8;
        if (c0 > Mg - 4) c0 = Mg - 4;                 // clamped lanes have P==0
        if (c1 > Mg - 4) c1 = Mg - 4;
        f16x8 vf = mk8(ld4(vp + c0), ld4(vp + c1));
        o = MFMA(pa, vf, o);
    }

    // store: C[q][dh]: col = lane&31 = dh, row = crow = q
#pragma unroll
    for (int r = 0; r < 16; ++r) {
        int grow = 32 * c + (r & 3) + 8 * (r >> 2) + 4 * hi;
        AO[((size_t)b * Mg + grow) * 256 + h * 32 + l31] = (f16)o[r];
    }
}

// ---------------------------------------------------------------------------
// k_out: OUT = AO (fp16) x WoT.  grid = (2, 256).
// ---------------------------------------------------------------------------
__global__ __launch_bounds__(256) void k_out(const f16* __restrict__ A,
                                             const f16* __restrict__ WT,
                                             f16* __restrict__ OUT) {
    __shared__ f16 As[128 * 68];
    __shared__ f16 Ws[128 * 68];

    const int tid  = threadIdx.x;
    const int n0   = blockIdx.x * 128;
    const int m0   = blockIdx.y * 128;
    const int lane = tid & 63;
    const int wid  = tid >> 6;
    const int wm   = wid >> 1, wn = wid & 1;
    const int l31  = lane & 31, hi = lane >> 5;
    const f16* Wb  = WT + 3 * 65536;   // WoT

    f32x16 acc[2][2];
#pragma unroll
    for (int mi = 0; mi < 2; ++mi)
#pragma unroll
        for (int ni = 0; ni < 2; ++ni)
#pragma unroll
            for (int e = 0; e < 16; ++e) acc[mi][ni][e] = 0.f;

    for (int k0 = 0; k0 < 256; k0 += 64) {
#pragma unroll
        for (int i = 0; i < 4; ++i) {
            int flat = i * 256 + tid;
            int r = flat >> 3, cc = (flat & 7) << 3;
            const f16* src = A + (size_t)(m0 + r) * 256 + k0 + cc;
            *reinterpret_cast<f16x4*>(&As[r * 68 + cc])     = ld4(src);
            *reinterpret_cast<f16x4*>(&As[r * 68 + cc + 4]) = ld4(src + 4);
        }
#pragma unroll
        for (int i = 0; i < 4; ++i) {
            int flat = i * 256 + tid;
            int r = flat >> 3, cc = (flat & 7) << 3;
            const f16* src = Wb + (size_t)(n0 + r) * 256 + k0 + cc;
            *reinterpret_cast<f16x4*>(&Ws[r * 68 + cc])     = ld4(src);
            *reinterpret_cast<f16x4*>(&Ws[r * 68 + cc + 4]) = ld4(src + 4);
        }
        __syncthreads();

#pragma unroll
        for (int ks = 0; ks < 4; ++ks) {
            const int kl = ks * 16 + 4 * hi;
            f16x8 af[2], bf[2];
#pragma unroll
            for (int mi = 0; mi < 2; ++mi) {
                const f16* p = &As[(wm * 64 + mi * 32 + l31) * 68 + kl];
                af[mi] = mk8(ld4(p), ld4(p + 8));
            }
#pragma unroll
            for (int ni = 0; ni < 2; ++ni) {
                const f16* p = &Ws[(wn * 64 + ni * 32 + l31) * 68 + kl];
                bf[ni] = mk8(ld4(p), ld4(p + 8));
            }
#pragma unroll
            for (int mi = 0; mi < 2; ++mi)
#pragma unroll
                for (int ni = 0; ni < 2; ++ni)
                    acc[mi][ni] = MFMA(af[mi], bf[ni], acc[mi][ni]);
        }
        __syncthreads();
    }

#pragma unroll
    for (int mi = 0; mi < 2; ++mi)
#pragma unroll
        for (int ni = 0; ni < 2; ++ni) {
            const int gcol  = n0 + wn * 64 + ni * 32 + l31;
            const int mbase = m0 + wm * 64 + mi * 32 + 4 * hi;
#pragma unroll
            for (int r = 0; r < 16; ++r) {
                int grow = mbase + (r & 3) + 8 * (r >> 2);
                OUT[(size_t)grow * 256 + gcol] = (f16)acc[mi][ni][r];
            }
        }
}

// ---------------------------------------------------------------------------
// k_seg: segment mean per (token, batch). grid = (2048, 2), block = 256.
// ---------------------------------------------------------------------------
__global__ __launch_bounds__(256) void k_seg(const f16* __restrict__ OUT,
                                             const int* __restrict__ uid,
                                             const float* __restrict__ mask,
                                             float* __restrict__ out) {
    const int t = blockIdx.x, b = blockIdx.y;
    const int d = threadIdx.x;
    const int* u = uid + b * Mg;

    int lo = 0, hi = Mg;
    while (lo < hi) { int mid = (lo + hi) >> 1; if (u[mid] < t) lo = mid + 1; else hi = mid; }
    int lo2 = lo, hi2 = Mg;
    while (lo2 < hi2) { int mid = (lo2 + hi2) >> 1; if (u[mid] < t + 1) lo2 = mid + 1; else hi2 = mid; }

    float sum = 0.f, cnt = 0.f;
    for (int m = lo; m < lo2; ++m) {
        float msk = mask[b * Mg + m];
        sum += msk * (float)OUT[((size_t)b * Mg + m) * 256 + d];
        cnt += msk;
    }
    out[((size_t)b * Ntok + t) * 256 + d] = sum / (cnt + 1e-8f);
}

// ---------------------------------------------------------------------------
extern "C" void kernel_launch(void* const* d_in, const int* in_sizes, int n_in,
                              void* d_out, int out_size, void* d_ws, size_t ws_size,
                              hipStream_t stream) {
    const float* f_atom = (const float*)d_in[0];
    const float* amask  = (const float*)d_in[1];
    const float* Wq     = (const float*)d_in[2];
    const float* Wk     = (const float*)d_in[3];
    const float* Wv     = (const float*)d_in[4];
    const float* Wo     = (const float*)d_in[5];
    const int*   uid    = (const int*)d_in[6];

    // workspace layout (fp16 units)
    const size_t HALF_WT  = 4 * 65536;           //  0.5 MB
    const size_t HALF_MAT = (size_t)Bg * Mg * Dg; // 8.4 M halves = 16.8 MB
    const size_t needed_bytes = (HALF_WT + 5 * HALF_MAT) * sizeof(f16);
    if (ws_size < needed_bytes) return;

    f16* WT  = (f16*)d_ws;
    f16* Qb  = WT + HALF_WT;
    f16* Kb  = Qb + HALF_MAT;
    f16* VTb = Kb + HALF_MAT;
    f16* AOb = VTb + HALF_MAT;
    f16* OUTb = AOb + HALF_MAT;

    k_wt  <<<dim3(1024), 256, 0, stream>>>(Wq, Wk, Wv, Wo, WT);
    k_qkv <<<dim3(6, 256), 256, 0, stream>>>(f_atom, WT, Qb, Kb, VTb);
    k_attn<<<dim3(Hg, Cg, Bg), 64, 0, stream>>>(Qb, Kb, VTb, AOb);
    k_out <<<dim3(2, 256), 256, 0, stream>>>(AOb, WT, OUTb);
    k_seg <<<dim3(Ntok, Bg), 256, 0, stream>>>(OUTb, uid, amask, (float*)d_out);
}

// Round 2
// 110.181 us; speedup vs baseline: 1.2336x; 1.2336x over previous
//
#include <hip/hip_runtime.h>

typedef _Float16 f16;
typedef _Float16 f16x4 __attribute__((ext_vector_type(4)));
typedef _Float16 f16x8 __attribute__((ext_vector_type(8)));
typedef float    f32x16 __attribute__((ext_vector_type(16)));

#define MFMA(a, b, c) __builtin_amdgcn_mfma_f32_32x32x16_f16((a), (b), (c), 0, 0, 0)

static constexpr int Mg   = 16384;
static constexpr int Bg   = 2;
static constexpr int Dg   = 256;
static constexpr int Hg   = 8;
static constexpr int Cg   = 512;
static constexpr int Ntok = 2048;
static constexpr float QSCALE = 0.17677669529663687f; // 1/sqrt(32)

typedef __attribute__((address_space(3))) f16 lds_f16;
typedef __attribute__((address_space(1))) const void gbl_cv;
typedef __attribute__((address_space(3))) void lds_v;

static __device__ __forceinline__ void gll16(const f16* g, f16* l) {
    __builtin_amdgcn_global_load_lds((gbl_cv*)g, (lds_v*)l, 16, 0, 0);
}
static __device__ __forceinline__ f16x4 ld4(const f16* p) {
    return *reinterpret_cast<const f16x4*>(p);
}
static __device__ __forceinline__ f16x8 mk8(f16x4 a, f16x4 b) {
    f16x8 r;
    r[0] = a[0]; r[1] = a[1]; r[2] = a[2]; r[3] = a[3];
    r[4] = b[0]; r[5] = b[1]; r[6] = b[2]; r[7] = b[3];
    return r;
}

// ---------------------------------------------------------------------------
// k_wt: W[k][n] fp32 -> Wsw[w][n][k-swizzled] fp16 (slot^(n&7) per 64-col grp)
// ---------------------------------------------------------------------------
__global__ __launch_bounds__(256) void k_wt(const float* __restrict__ Wq,
                                            const float* __restrict__ Wk,
                                            const float* __restrict__ Wv,
                                            const float* __restrict__ Wo,
                                            f16* __restrict__ Wsw) {
    int idx = blockIdx.x * 256 + threadIdx.x;
    int w   = idx >> 16;
    int rem = idx & 65535;
    int k   = rem >> 8;
    int n   = rem & 255;
    const float* W = (w == 0) ? Wq : (w == 1) ? Wk : (w == 2) ? Wv : Wo;
    int k0  = k & ~63;
    int sst = ((k >> 3) & 7) ^ (n & 7);
    Wsw[w * 65536 + n * 256 + k0 + (sst << 3) + (k & 7)] = (f16)W[k * 256 + n];
}

// ---------------------------------------------------------------------------
// k_cvt: A fp32 [32768][256] -> Ah fp16, swizzled (slot^(m&7) per 64-col grp)
// ---------------------------------------------------------------------------
__global__ __launch_bounds__(256) void k_cvt(const float* __restrict__ A,
                                             f16* __restrict__ Ah) {
    int g  = blockIdx.x * 256 + threadIdx.x;   // one 8-elem granule each
    int m  = g >> 5, sg = g & 31;
    int k0 = (sg >> 3) << 6;
    int sst = (sg & 7) ^ (m & 7);
    const float* src = A + (size_t)m * 256 + sg * 8;
    float4 v0 = *reinterpret_cast<const float4*>(src);
    float4 v1 = *reinterpret_cast<const float4*>(src + 4);
    f16x8 h8 = { (f16)v0.x, (f16)v0.y, (f16)v0.z, (f16)v0.w,
                 (f16)v1.x, (f16)v1.y, (f16)v1.z, (f16)v1.w };
    *reinterpret_cast<f16x8*>(Ah + (size_t)m * 256 + k0 + (sst << 3)) = h8;
}

// ---------------------------------------------------------------------------
// k_qkv: Ah(sw) x Wsw -> Q(scaled), K, VT.  128x128 tile, BK=64, dbuf LDS,
// global_load_lds(16B) staging, XCD-chunked swizzle. grid 1536, 256 thr.
// ---------------------------------------------------------------------------
__global__ __launch_bounds__(256, 2) void k_qkv(const f16* __restrict__ Ah,
                                                const f16* __restrict__ Wsw,
                                                f16* __restrict__ Qo,
                                                f16* __restrict__ Ko,
                                                f16* __restrict__ VT) {
    __shared__ f16 As[2][128 * 64];
    __shared__ f16 Ws[2][128 * 64];

    const int tid = threadIdx.x;
    const int d   = blockIdx.x;
    const int lin = (d & 7) * 192 + (d >> 3);   // 6 siblings of a row-tile -> same XCD
    const int ytile = lin / 6;
    const int x6    = lin % 6;
    const int wix   = x6 >> 1;                  // 0=Q 1=K 2=V
    const int nt    = x6 & 1;
    const int m0 = ytile * 128, n0 = nt * 128;

    const f16* Asrc = Ah + (size_t)m0 * 256;
    const f16* Wsrc = Wsw + wix * 65536 + (size_t)n0 * 256;

    const int lane = tid & 63, wid = tid >> 6;
    const int wm = wid >> 1, wn = wid & 1;
    const int l31 = lane & 31, hi = lane >> 5;
    const int rb7 = l31 & 7;

    f32x16 acc[2][2];
#pragma unroll
    for (int mi = 0; mi < 2; ++mi)
#pragma unroll
        for (int ni = 0; ni < 2; ++ni)
#pragma unroll
            for (int e = 0; e < 16; ++e) acc[mi][ni][e] = 0.f;

#define STAGE(K0, BB)                                                          \
    {                                                                          \
        _Pragma("unroll")                                                      \
        for (int i = 0; i < 4; ++i) {                                          \
            int g = i * 256 + tid;                                             \
            int r = g >> 3, s = g & 7;                                         \
            gll16(Asrc + r * 256 + (K0) + s * 8, &As[BB][g * 8]);              \
            gll16(Wsrc + r * 256 + (K0) + s * 8, &Ws[BB][g * 8]);              \
        }                                                                      \
    }

#define COMPUTE(BB)                                                            \
    {                                                                          \
        _Pragma("unroll")                                                      \
        for (int ks = 0; ks < 4; ++ks) {                                       \
            const int sl = (2 * ks + hi) ^ rb7;                                \
            f16x8 af[2], bf[2];                                                \
            _Pragma("unroll")                                                  \
            for (int mi = 0; mi < 2; ++mi)                                     \
                af[mi] = *(const f16x8*)&As[BB][(wm * 64 + mi * 32 + l31) * 64 + sl * 8]; \
            _Pragma("unroll")                                                  \
            for (int ni = 0; ni < 2; ++ni)                                     \
                bf[ni] = *(const f16x8*)&Ws[BB][(wn * 64 + ni * 32 + l31) * 64 + sl * 8]; \
            _Pragma("unroll")                                                  \
            for (int mi = 0; mi < 2; ++mi)                                     \
                _Pragma("unroll")                                              \
                for (int ni = 0; ni < 2; ++ni)                                 \
                    acc[mi][ni] = MFMA(af[mi], bf[ni], acc[mi][ni]);           \
        }                                                                      \
    }

    STAGE(0, 0);
    __syncthreads();
    STAGE(64, 1);
    COMPUTE(0);
    __syncthreads();
    STAGE(128, 0);
    COMPUTE(1);
    __syncthreads();
    STAGE(192, 1);
    COMPUTE(0);
    __syncthreads();
    COMPUTE(1);

    // epilogue
#pragma unroll
    for (int mi = 0; mi < 2; ++mi) {
#pragma unroll
        for (int ni = 0; ni < 2; ++ni) {
            const int gcol  = n0 + wn * 64 + ni * 32 + l31;
            const int mbase = m0 + wm * 64 + mi * 32 + 4 * hi;
            if (wix == 0) {
#pragma unroll
                for (int r = 0; r < 16; ++r) {
                    int grow = mbase + (r & 3) + 8 * (r >> 2);
                    Qo[(size_t)grow * 256 + gcol] = (f16)(acc[mi][ni][r] * QSCALE);
                }
            } else if (wix == 1) {
#pragma unroll
                for (int r = 0; r < 16; ++r) {
                    int grow = mbase + (r & 3) + 8 * (r >> 2);
                    Ko[(size_t)grow * 256 + gcol] = (f16)acc[mi][ni][r];
                }
            } else {
#pragma unroll
                for (int rq = 0; rq < 4; ++rq) {
                    f16x4 pv = { (f16)acc[mi][ni][rq * 4 + 0], (f16)acc[mi][ni][rq * 4 + 1],
                                 (f16)acc[mi][ni][rq * 4 + 2], (f16)acc[mi][ni][rq * 4 + 3] };
                    int mrow = mbase + 8 * rq;
                    int bb = mrow >> 14, mm = mrow & 16383;
                    *reinterpret_cast<f16x4*>(VT + (size_t)bb * (256 * 16384) +
                                              (size_t)gcol * 16384 + mm) = pv;
                }
            }
        }
    }
#undef STAGE
#undef COMPUTE
}

// ---------------------------------------------------------------------------
// k_attn: one wave per (head, qblock, batch). grid (8,512,2), block 64.
// d%8==h pins each head to one XCD -> K/V window L2 locality for free.
// Writes AO in the swizzled layout for k_out's staging.
// ---------------------------------------------------------------------------
__global__ __launch_bounds__(64) void k_attn(const f16* __restrict__ Qo,
                                             const f16* __restrict__ Ko,
                                             const f16* __restrict__ VT,
                                             f16* __restrict__ AOsw) {
    const int h = blockIdx.x, c = blockIdx.y, b = blockIdx.z;
    const int lane = threadIdx.x;
    const int l31 = lane & 31, hi = lane >> 5;

    const int s0   = (32 * c - 48 > 0) ? (32 * c - 48) : 0;
    const int e0   = (32 * c + 80 < Mg) ? (32 * c + 80) : Mg;
    const int wlen = e0 - s0;

    const f16* qp = Qo + ((size_t)b * Mg + 32 * c + l31) * 256 + h * 32;
    f16x8 qf0 = *reinterpret_cast<const f16x8*>(qp + 8 * hi);
    f16x8 qf1 = *reinterpret_cast<const f16x8*>(qp + 16 + 8 * hi);

    f32x16 p4[4];
#pragma unroll
    for (int t = 0; t < 4; ++t)
#pragma unroll
        for (int e = 0; e < 16; ++e) p4[t][e] = 0.f;

#pragma unroll
    for (int t = 0; t < 4; ++t) {
        int kr = s0 + 32 * t + l31;
        if (kr > Mg - 1) kr = Mg - 1;
        const f16* kp = Ko + ((size_t)b * Mg + kr) * 256 + h * 32;
        f16x8 kf0 = *reinterpret_cast<const f16x8*>(kp + 8 * hi);
        f16x8 kf1 = *reinterpret_cast<const f16x8*>(kp + 16 + 8 * hi);
        p4[t] = MFMA(kf0, qf0, p4[t]);
        p4[t] = MFMA(kf1, qf1, p4[t]);
    }

    float mx = -3e38f;
#pragma unroll
    for (int t = 0; t < 4; ++t)
#pragma unroll
        for (int r = 0; r < 16; ++r) {
            int kk = 32 * t + (r & 3) + 8 * (r >> 2) + 4 * hi;
            if (kk < wlen) mx = fmaxf(mx, p4[t][r]);
        }
    mx = fmaxf(mx, __shfl_xor(mx, 32));

    float sum = 0.f;
#pragma unroll
    for (int t = 0; t < 4; ++t)
#pragma unroll
        for (int r = 0; r < 16; ++r) {
            int kk = 32 * t + (r & 3) + 8 * (r >> 2) + 4 * hi;
            float ev = (kk < wlen) ? __expf(p4[t][r] - mx) : 0.f;
            p4[t][r] = ev;
            sum += ev;
        }
    sum += __shfl_xor(sum, 32);
    const float inv = 1.f / sum;
#pragma unroll
    for (int t = 0; t < 4; ++t)
#pragma unroll
        for (int e = 0; e < 16; ++e) p4[t][e] *= inv;

    f32x16 o;
#pragma unroll
    for (int e = 0; e < 16; ++e) o[e] = 0.f;

    const f16* vp = VT + ((size_t)b * 256 + h * 32 + l31) * Mg;
#pragma unroll
    for (int s = 0; s < 8; ++s) {
        f16x8 pa;
#pragma unroll
        for (int e = 0; e < 8; ++e) pa[e] = (f16)(p4[s >> 1][8 * (s & 1) + e]);
        int c0 = s0 + 16 * s + 4 * hi;
        int c1 = c0 + 8;
        if (c0 > Mg - 4) c0 = Mg - 4;
        if (c1 > Mg - 4) c1 = Mg - 4;
        f16x8 vf = mk8(ld4(vp + c0), ld4(vp + c1));
        o = MFMA(pa, vf, o);
    }

#pragma unroll
    for (int r = 0; r < 16; ++r) {
        int mrow = 32 * c + (r & 3) + 8 * (r >> 2) + 4 * hi;
        int cc   = h * 32 + l31;
        int sl   = ((cc >> 3) & 7) ^ (mrow & 7);
        int cs   = (cc & ~63) | (sl << 3) | (cc & 7);
        AOsw[((size_t)b * Mg + mrow) * 256 + cs] = (f16)o[r];
    }
}

// ---------------------------------------------------------------------------
// k_out: AOsw x Wo -> OUT (plain).  Same structure as k_qkv. grid 512.
// ---------------------------------------------------------------------------
__global__ __launch_bounds__(256, 2) void k_out(const f16* __restrict__ AOsw,
                                                const f16* __restrict__ Wsw,
                                                f16* __restrict__ OUT) {
    __shared__ f16 As[2][128 * 64];
    __shared__ f16 Ws[2][128 * 64];

    const int tid = threadIdx.x;
    const int d   = blockIdx.x;
    const int lin = (d & 7) * 64 + (d >> 3);
    const int ytile = lin >> 1;
    const int nt    = lin & 1;
    const int m0 = ytile * 128, n0 = nt * 128;

    const f16* Asrc = AOsw + (size_t)m0 * 256;
    const f16* Wsrc = Wsw + 3 * 65536 + (size_t)n0 * 256;

    const int lane = tid & 63, wid = tid >> 6;
    const int wm = wid >> 1, wn = wid & 1;
    const int l31 = lane & 31, hi = lane >> 5;
    const int rb7 = l31 & 7;

    f32x16 acc[2][2];
#pragma unroll
    for (int mi = 0; mi < 2; ++mi)
#pragma unroll
        for (int ni = 0; ni < 2; ++ni)
#pragma unroll
            for (int e = 0; e < 16; ++e) acc[mi][ni][e] = 0.f;

#define STAGE(K0, BB)                                                          \
    {                                                                          \
        _Pragma("unroll")                                                      \
        for (int i = 0; i < 4; ++i) {                                          \
            int g = i * 256 + tid;                                             \
            int r = g >> 3, s = g & 7;                                         \
            gll16(Asrc + r * 256 + (K0) + s * 8, &As[BB][g * 8]);              \
            gll16(Wsrc + r * 256 + (K0) + s * 8, &Ws[BB][g * 8]);              \
        }                                                                      \
    }

#define COMPUTE(BB)                                                            \
    {                                                                          \
        _Pragma("unroll")                                                      \
        for (int ks = 0; ks < 4; ++ks) {                                       \
            const int sl = (2 * ks + hi) ^ rb7;                                \
            f16x8 af[2], bf[2];                                                \
            _Pragma("unroll")                                                  \
            for (int mi = 0; mi < 2; ++mi)                                     \
                af[mi] = *(const f16x8*)&As[BB][(wm * 64 + mi * 32 + l31) * 64 + sl * 8]; \
            _Pragma("unroll")                                                  \
            for (int ni = 0; ni < 2; ++ni)                                     \
                bf[ni] = *(const f16x8*)&Ws[BB][(wn * 64 + ni * 32 + l31) * 64 + sl * 8]; \
            _Pragma("unroll")                                                  \
            for (int mi = 0; mi < 2; ++mi)                                     \
                _Pragma("unroll")                                              \
                for (int ni = 0; ni < 2; ++ni)                                 \
                    acc[mi][ni] = MFMA(af[mi], bf[ni], acc[mi][ni]);           \
        }                                                                      \
    }

    STAGE(0, 0);
    __syncthreads();
    STAGE(64, 1);
    COMPUTE(0);
    __syncthreads();
    STAGE(128, 0);
    COMPUTE(1);
    __syncthreads();
    STAGE(192, 1);
    COMPUTE(0);
    __syncthreads();
    COMPUTE(1);

#pragma unroll
    for (int mi = 0; mi < 2; ++mi)
#pragma unroll
        for (int ni = 0; ni < 2; ++ni) {
            const int gcol  = n0 + wn * 64 + ni * 32 + l31;
            const int mbase = m0 + wm * 64 + mi * 32 + 4 * hi;
#pragma unroll
            for (int r = 0; r < 16; ++r) {
                int grow = mbase + (r & 3) + 8 * (r >> 2);
                OUT[(size_t)grow * 256 + gcol] = (f16)acc[mi][ni][r];
            }
        }
#undef STAGE
#undef COMPUTE
}

// ---------------------------------------------------------------------------
// k_seg: segment mean per (token, batch). grid (2048, 2), block 256.
// ---------------------------------------------------------------------------
__global__ __launch_bounds__(256) void k_seg(const f16* __restrict__ OUT,
                                             const int* __restrict__ uid,
                                             const float* __restrict__ mask,
                                             float* __restrict__ out) {
    const int t = blockIdx.x, b = blockIdx.y;
    const int d = threadIdx.x;
    const int* u = uid + b * Mg;

    int lo = 0, hi = Mg;
    while (lo < hi) { int mid = (lo + hi) >> 1; if (u[mid] < t) lo = mid + 1; else hi = mid; }
    int lo2 = lo, hi2 = Mg;
    while (lo2 < hi2) { int mid = (lo2 + hi2) >> 1; if (u[mid] < t + 1) lo2 = mid + 1; else hi2 = mid; }

    float sum = 0.f, cnt = 0.f;
    for (int m = lo; m < lo2; ++m) {
        float msk = mask[b * Mg + m];
        sum += msk * msk * (float)OUT[((size_t)b * Mg + m) * 256 + d];
        cnt += msk;
    }
    out[((size_t)b * Ntok + t) * 256 + d] = sum / (cnt + 1e-8f);
}

// ---------------------------------------------------------------------------
extern "C" void kernel_launch(void* const* d_in, const int* in_sizes, int n_in,
                              void* d_out, int out_size, void* d_ws, size_t ws_size,
                              hipStream_t stream) {
    const float* f_atom = (const float*)d_in[0];
    const float* amask  = (const float*)d_in[1];
    const float* Wq     = (const float*)d_in[2];
    const float* Wk     = (const float*)d_in[3];
    const float* Wv     = (const float*)d_in[4];
    const float* Wo     = (const float*)d_in[5];
    const int*   uid    = (const int*)d_in[6];

    const size_t HALF_WT  = 4 * 65536;
    const size_t HALF_MAT = (size_t)Bg * Mg * Dg;
    const size_t needed_bytes = (HALF_WT + 5 * HALF_MAT) * sizeof(f16);
    if (ws_size < needed_bytes) return;

    f16* Wsw  = (f16*)d_ws;
    f16* Ah   = Wsw + HALF_WT;       // also reused as AOsw after k_qkv
    f16* Qb   = Ah + HALF_MAT;
    f16* Kb   = Qb + HALF_MAT;
    f16* VTb  = Kb + HALF_MAT;
    f16* OUTb = VTb + HALF_MAT;
    f16* AOsw = Ah;                  // alias: Ah dead after k_qkv

    k_wt  <<<dim3(1024), 256, 0, stream>>>(Wq, Wk, Wv, Wo, Wsw);
    k_cvt <<<dim3(4096), 256, 0, stream>>>(f_atom, Ah);
    k_qkv <<<dim3(1536), 256, 0, stream>>>(Ah, Wsw, Qb, Kb, VTb);
    k_attn<<<dim3(Hg, Cg, Bg), 64, 0, stream>>>(Qb, Kb, VTb, AOsw);
    k_out <<<dim3(512), 256, 0, stream>>>(AOsw, Wsw, OUTb);
    k_seg <<<dim3(Ntok, Bg), 256, 0, stream>>>(OUTb, uid, amask, (float*)d_out);
}

// Round 3
// 102.879 us; speedup vs baseline: 1.3212x; 1.0710x over previous
//
#include <hip/hip_runtime.h>

typedef _Float16 f16;
typedef _Float16 f16x4 __attribute__((ext_vector_type(4)));
typedef _Float16 f16x8 __attribute__((ext_vector_type(8)));
typedef float    f32x16 __attribute__((ext_vector_type(16)));

#define MFMA(a, b, c) __builtin_amdgcn_mfma_f32_32x32x16_f16((a), (b), (c), 0, 0, 0)

static constexpr int Mg   = 16384;
static constexpr int Bg   = 2;
static constexpr int Dg   = 256;
static constexpr int Hg   = 8;
static constexpr int Cg   = 512;
static constexpr int Ntok = 2048;
static constexpr float QSCALE = 0.17677669529663687f; // 1/sqrt(32)

typedef __attribute__((address_space(1))) const void gbl_cv;
typedef __attribute__((address_space(3))) void lds_v;

static __device__ __forceinline__ void gll16(const f16* g, f16* l) {
    __builtin_amdgcn_global_load_lds((gbl_cv*)g, (lds_v*)l, 16, 0, 0);
}
static __device__ __forceinline__ f16x4 ld4(const f16* p) {
    return *reinterpret_cast<const f16x4*>(p);
}
static __device__ __forceinline__ f16x8 mk8(f16x4 a, f16x4 b) {
    f16x8 r;
    r[0] = a[0]; r[1] = a[1]; r[2] = a[2]; r[3] = a[3];
    r[4] = b[0]; r[5] = b[1]; r[6] = b[2]; r[7] = b[3];
    return r;
}

// ---------------------------------------------------------------------------
// k_wt: W[k][n] fp32 -> Wsw[w][n][k-swizzled] fp16 (slot^(n&7) per 64-col grp)
// ---------------------------------------------------------------------------
__global__ __launch_bounds__(256) void k_wt(const float* __restrict__ Wq,
                                            const float* __restrict__ Wk,
                                            const float* __restrict__ Wv,
                                            const float* __restrict__ Wo,
                                            f16* __restrict__ Wsw) {
    int idx = blockIdx.x * 256 + threadIdx.x;
    int w   = idx >> 16;
    int rem = idx & 65535;
    int k   = rem >> 8;
    int n   = rem & 255;
    const float* W = (w == 0) ? Wq : (w == 1) ? Wk : (w == 2) ? Wv : Wo;
    int k0  = k & ~63;
    int sst = ((k >> 3) & 7) ^ (n & 7);
    Wsw[w * 65536 + n * 256 + k0 + (sst << 3) + (k & 7)] = (f16)W[k * 256 + n];
}

// ---------------------------------------------------------------------------
// k_cvt: A fp32 [32768][256] -> Ah fp16, swizzled (slot^(m&7) per 64-col grp)
// ---------------------------------------------------------------------------
__global__ __launch_bounds__(256) void k_cvt(const float* __restrict__ A,
                                             f16* __restrict__ Ah) {
    int g  = blockIdx.x * 256 + threadIdx.x;
    int m  = g >> 5, sg = g & 31;
    int k0 = (sg >> 3) << 6;
    int sst = (sg & 7) ^ (m & 7);
    const float* src = A + (size_t)m * 256 + sg * 8;
    float4 v0 = *reinterpret_cast<const float4*>(src);
    float4 v1 = *reinterpret_cast<const float4*>(src + 4);
    f16x8 h8 = { (f16)v0.x, (f16)v0.y, (f16)v0.z, (f16)v0.w,
                 (f16)v1.x, (f16)v1.y, (f16)v1.z, (f16)v1.w };
    *reinterpret_cast<f16x8*>(Ah + (size_t)m * 256 + k0 + (sst << 3)) = h8;
}

// ---------------------------------------------------------------------------
// k_qkv: Ah(sw) x Wsw -> Q(scaled), K, VT. 128x128 tile, BK=64, dbuf LDS,
// global_load_lds(16B) staging, XCD-chunked swizzle. grid 1536, 256 thr.
// ---------------------------------------------------------------------------
__global__ __launch_bounds__(256, 2) void k_qkv(const f16* __restrict__ Ah,
                                                const f16* __restrict__ Wsw,
                                                f16* __restrict__ Qo,
                                                f16* __restrict__ Ko,
                                                f16* __restrict__ VT) {
    __shared__ f16 As[2][128 * 64];
    __shared__ f16 Ws[2][128 * 64];

    const int tid = threadIdx.x;
    const int d   = blockIdx.x;
    const int lin = (d & 7) * 192 + (d >> 3);
    const int ytile = lin / 6;
    const int x6    = lin % 6;
    const int wix   = x6 >> 1;
    const int nt    = x6 & 1;
    const int m0 = ytile * 128, n0 = nt * 128;

    const f16* Asrc = Ah + (size_t)m0 * 256;
    const f16* Wsrc = Wsw + wix * 65536 + (size_t)n0 * 256;

    const int lane = tid & 63, wid = tid >> 6;
    const int wm = wid >> 1, wn = wid & 1;
    const int l31 = lane & 31, hi = lane >> 5;
    const int rb7 = l31 & 7;

    f32x16 acc[2][2];
#pragma unroll
    for (int mi = 0; mi < 2; ++mi)
#pragma unroll
        for (int ni = 0; ni < 2; ++ni)
#pragma unroll
            for (int e = 0; e < 16; ++e) acc[mi][ni][e] = 0.f;

#define STAGE(K0, BB)                                                          \
    {                                                                          \
        _Pragma("unroll")                                                      \
        for (int i = 0; i < 4; ++i) {                                          \
            int g = i * 256 + tid;                                             \
            int r = g >> 3, s = g & 7;                                         \
            gll16(Asrc + r * 256 + (K0) + s * 8, &As[BB][g * 8]);              \
            gll16(Wsrc + r * 256 + (K0) + s * 8, &Ws[BB][g * 8]);              \
        }                                                                      \
    }

#define COMPUTE(BB)                                                            \
    {                                                                          \
        _Pragma("unroll")                                                      \
        for (int ks = 0; ks < 4; ++ks) {                                       \
            const int sl = (2 * ks + hi) ^ rb7;                                \
            f16x8 af[2], bf[2];                                                \
            _Pragma("unroll")                                                  \
            for (int mi = 0; mi < 2; ++mi)                                     \
                af[mi] = *(const f16x8*)&As[BB][(wm * 64 + mi * 32 + l31) * 64 + sl * 8]; \
            _Pragma("unroll")                                                  \
            for (int ni = 0; ni < 2; ++ni)                                     \
                bf[ni] = *(const f16x8*)&Ws[BB][(wn * 64 + ni * 32 + l31) * 64 + sl * 8]; \
            _Pragma("unroll")                                                  \
            for (int mi = 0; mi < 2; ++mi)                                     \
                _Pragma("unroll")                                              \
                for (int ni = 0; ni < 2; ++ni)                                 \
                    acc[mi][ni] = MFMA(af[mi], bf[ni], acc[mi][ni]);           \
        }                                                                      \
    }

    STAGE(0, 0);
    __syncthreads();
    STAGE(64, 1);
    COMPUTE(0);
    __syncthreads();
    STAGE(128, 0);
    COMPUTE(1);
    __syncthreads();
    STAGE(192, 1);
    COMPUTE(0);
    __syncthreads();
    COMPUTE(1);

#pragma unroll
    for (int mi = 0; mi < 2; ++mi) {
#pragma unroll
        for (int ni = 0; ni < 2; ++ni) {
            const int gcol  = n0 + wn * 64 + ni * 32 + l31;
            const int mbase = m0 + wm * 64 + mi * 32 + 4 * hi;
            if (wix == 0) {
#pragma unroll
                for (int r = 0; r < 16; ++r) {
                    int grow = mbase + (r & 3) + 8 * (r >> 2);
                    Qo[(size_t)grow * 256 + gcol] = (f16)(acc[mi][ni][r] * QSCALE);
                }
            } else if (wix == 1) {
#pragma unroll
                for (int r = 0; r < 16; ++r) {
                    int grow = mbase + (r & 3) + 8 * (r >> 2);
                    Ko[(size_t)grow * 256 + gcol] = (f16)acc[mi][ni][r];
                }
            } else {
#pragma unroll
                for (int rq = 0; rq < 4; ++rq) {
                    f16x4 pv = { (f16)acc[mi][ni][rq * 4 + 0], (f16)acc[mi][ni][rq * 4 + 1],
                                 (f16)acc[mi][ni][rq * 4 + 2], (f16)acc[mi][ni][rq * 4 + 3] };
                    int mrow = mbase + 8 * rq;
                    int bb = mrow >> 14, mm = mrow & 16383;
                    *reinterpret_cast<f16x4*>(VT + (size_t)bb * (256 * 16384) +
                                              (size_t)gcol * 16384 + mm) = pv;
                }
            }
        }
    }
#undef STAGE
#undef COMPUTE
}

// ---------------------------------------------------------------------------
// k_attn v2: one 8-wave block per (c,b); wave = head. K/V staged in LDS via
// global_load_lds with XOR-swizzle (pre-swizzled per-lane SOURCE, linear dest,
// swizzled read). Counted vmcnt: QK^T+softmax overlap the V staging.
// grid 1024 (XCD-chunked), block 512.
// ---------------------------------------------------------------------------
__global__ __launch_bounds__(512, 1) void k_attn(const f16* __restrict__ Qo,
                                                 const f16* __restrict__ Ko,
                                                 const f16* __restrict__ VT,
                                                 f16* __restrict__ AOsw) {
    __shared__ f16 Ks[128 * 256];   // [r][s16^((s0+r)&31)] : 64 KB
    __shared__ f16 Vs[256 * 128];   // [d][g16^(d&15)]      : 64 KB

    const int tid  = threadIdx.x;
    const int dblk = blockIdx.x;
    const int lin  = (dblk & 7) * 128 + (dblk >> 3);  // contiguous (b,c) per XCD
    const int b    = lin >> 9;
    const int c    = lin & 511;
    const int h    = tid >> 6;          // wave = head
    const int lane = tid & 63;
    const int l31  = lane & 31, hi = lane >> 5;

    const int s0   = (32 * c - 48 > 0) ? (32 * c - 48) : 0;
    const int e0   = (32 * c + 80 < Mg) ? (32 * c + 80) : Mg;
    const int wlen = e0 - s0;

    // ---- stage K window (8 insts/thread), then V window (8 insts/thread)
    const f16* Kbase = Ko + (size_t)b * Mg * 256;
#pragma unroll
    for (int i = 0; i < 8; ++i) {
        int g = i * 512 + tid;
        int r = g >> 5, s = g & 31;
        int gr  = s0 + r;
        int key = gr & 31;
        int grc = (gr < Mg) ? gr : (Mg - 1);
        gll16(Kbase + (size_t)grc * 256 + ((s ^ key) << 3), &Ks[g * 8]);
    }
    __builtin_amdgcn_sched_barrier(0);
    const f16* Vbase = VT + (size_t)b * 256 * Mg;
#pragma unroll
    for (int i = 0; i < 8; ++i) {
        int g = i * 512 + tid;
        int dd = g >> 4, G = g & 15;
        int cl = s0 + ((G ^ (dd & 15)) << 3);
        if (cl > Mg - 8) cl = Mg - 8;
        gll16(Vbase + (size_t)dd * Mg + cl, &Vs[g * 8]);
    }

    // ---- Q fragments from global (one-time, 2 loads)
    const f16* qp = Qo + ((size_t)b * Mg + 32 * c + l31) * 256 + h * 32;
    f16x8 qf0 = *reinterpret_cast<const f16x8*>(qp + 8 * hi);
    f16x8 qf1 = *reinterpret_cast<const f16x8*>(qp + 16 + 8 * hi);

    // ---- K ready (V may still be in flight)
    asm volatile("s_waitcnt vmcnt(8)" ::: "memory");
    __builtin_amdgcn_s_barrier();
    __builtin_amdgcn_sched_barrier(0);

    // ---- QK^T from LDS
    f32x16 p4[4];
#pragma unroll
    for (int t = 0; t < 4; ++t)
#pragma unroll
        for (int e = 0; e < 16; ++e) p4[t][e] = 0.f;

#pragma unroll
    for (int t = 0; t < 4; ++t) {
        int rr  = 32 * t + l31;
        int key = (s0 + rr) & 31;
        const f16* kb = &Ks[rr * 256];
        f16x8 kf0 = *(const f16x8*)&kb[((h * 4 + hi) ^ key) << 3];
        f16x8 kf1 = *(const f16x8*)&kb[((h * 4 + 2 + hi) ^ key) << 3];
        p4[t] = MFMA(kf0, qf0, p4[t]);
        p4[t] = MFMA(kf1, qf1, p4[t]);
    }

    // ---- masked in-register softmax (lane owns q-row l31; halves via lane^32)
    float mx = -3e38f;
#pragma unroll
    for (int t = 0; t < 4; ++t)
#pragma unroll
        for (int r = 0; r < 16; ++r) {
            int kk = 32 * t + (r & 3) + 8 * (r >> 2) + 4 * hi;
            if (kk < wlen) mx = fmaxf(mx, p4[t][r]);
        }
    mx = fmaxf(mx, __shfl_xor(mx, 32));

    float sum = 0.f;
#pragma unroll
    for (int t = 0; t < 4; ++t)
#pragma unroll
        for (int r = 0; r < 16; ++r) {
            int kk = 32 * t + (r & 3) + 8 * (r >> 2) + 4 * hi;
            float ev = (kk < wlen) ? __expf(p4[t][r] - mx) : 0.f;
            p4[t][r] = ev;
            sum += ev;
        }
    sum += __shfl_xor(sum, 32);
    const float inv = 1.f / sum;
#pragma unroll
    for (int t = 0; t < 4; ++t)
#pragma unroll
        for (int e = 0; e < 16; ++e) p4[t][e] *= inv;

    // ---- V ready
    asm volatile("s_waitcnt vmcnt(0)" ::: "memory");
    __builtin_amdgcn_s_barrier();
    __builtin_amdgcn_sched_barrier(0);

    // ---- PV from LDS
    f32x16 o;
#pragma unroll
    for (int e = 0; e < 16; ++e) o[e] = 0.f;

    const int d15 = l31 & 15;
    const f16* vb = &Vs[(h * 32 + l31) * 128];
#pragma unroll
    for (int s = 0; s < 8; ++s) {
        f16x8 pa;
#pragma unroll
        for (int e = 0; e < 8; ++e) pa[e] = (f16)(p4[s >> 1][8 * (s & 1) + e]);
        f16x4 v0 = *(const f16x4*)&vb[((((2 * s) ^ d15) << 3)) + 4 * hi];
        f16x4 v1 = *(const f16x4*)&vb[((((2 * s + 1) ^ d15) << 3)) + 4 * hi];
        f16x8 vf = mk8(v0, v1);
        o = MFMA(pa, vf, o);
    }

    // ---- store AO in k_out's swizzled layout
#pragma unroll
    for (int r = 0; r < 16; ++r) {
        int mrow = 32 * c + (r & 3) + 8 * (r >> 2) + 4 * hi;
        int cc   = h * 32 + l31;
        int sl   = ((cc >> 3) & 7) ^ (mrow & 7);
        int cs   = (cc & ~63) | (sl << 3) | (cc & 7);
        AOsw[((size_t)b * Mg + mrow) * 256 + cs] = (f16)o[r];
    }
}

// ---------------------------------------------------------------------------
// k_out: AOsw x Wo -> OUT (plain). grid 512.
// ---------------------------------------------------------------------------
__global__ __launch_bounds__(256, 2) void k_out(const f16* __restrict__ AOsw,
                                                const f16* __restrict__ Wsw,
                                                f16* __restrict__ OUT) {
    __shared__ f16 As[2][128 * 64];
    __shared__ f16 Ws[2][128 * 64];

    const int tid = threadIdx.x;
    const int d   = blockIdx.x;
    const int lin = (d & 7) * 64 + (d >> 3);
    const int ytile = lin >> 1;
    const int nt    = lin & 1;
    const int m0 = ytile * 128, n0 = nt * 128;

    const f16* Asrc = AOsw + (size_t)m0 * 256;
    const f16* Wsrc = Wsw + 3 * 65536 + (size_t)n0 * 256;

    const int lane = tid & 63, wid = tid >> 6;
    const int wm = wid >> 1, wn = wid & 1;
    const int l31 = lane & 31, hi = lane >> 5;
    const int rb7 = l31 & 7;

    f32x16 acc[2][2];
#pragma unroll
    for (int mi = 0; mi < 2; ++mi)
#pragma unroll
        for (int ni = 0; ni < 2; ++ni)
#pragma unroll
            for (int e = 0; e < 16; ++e) acc[mi][ni][e] = 0.f;

#define STAGE(K0, BB)                                                          \
    {                                                                          \
        _Pragma("unroll")                                                      \
        for (int i = 0; i < 4; ++i) {                                          \
            int g = i * 256 + tid;                                             \
            int r = g >> 3, s = g & 7;                                         \
            gll16(Asrc + r * 256 + (K0) + s * 8, &As[BB][g * 8]);              \
            gll16(Wsrc + r * 256 + (K0) + s * 8, &Ws[BB][g * 8]);              \
        }                                                                      \
    }

#define COMPUTE(BB)                                                            \
    {                                                                          \
        _Pragma("unroll")                                                      \
        for (int ks = 0; ks < 4; ++ks) {                                       \
            const int sl = (2 * ks + hi) ^ rb7;                                \
            f16x8 af[2], bf[2];                                                \
            _Pragma("unroll")                                                  \
            for (int mi = 0; mi < 2; ++mi)                                     \
                af[mi] = *(const f16x8*)&As[BB][(wm * 64 + mi * 32 + l31) * 64 + sl * 8]; \
            _Pragma("unroll")                                                  \
            for (int ni = 0; ni < 2; ++ni)                                     \
                bf[ni] = *(const f16x8*)&Ws[BB][(wn * 64 + ni * 32 + l31) * 64 + sl * 8]; \
            _Pragma("unroll")                                                  \
            for (int mi = 0; mi < 2; ++mi)                                     \
                _Pragma("unroll")                                              \
                for (int ni = 0; ni < 2; ++ni)                                 \
                    acc[mi][ni] = MFMA(af[mi], bf[ni], acc[mi][ni]);           \
        }                                                                      \
    }

    STAGE(0, 0);
    __syncthreads();
    STAGE(64, 1);
    COMPUTE(0);
    __syncthreads();
    STAGE(128, 0);
    COMPUTE(1);
    __syncthreads();
    STAGE(192, 1);
    COMPUTE(0);
    __syncthreads();
    COMPUTE(1);

#pragma unroll
    for (int mi = 0; mi < 2; ++mi)
#pragma unroll
        for (int ni = 0; ni < 2; ++ni) {
            const int gcol  = n0 + wn * 64 + ni * 32 + l31;
            const int mbase = m0 + wm * 64 + mi * 32 + 4 * hi;
#pragma unroll
            for (int r = 0; r < 16; ++r) {
                int grow = mbase + (r & 3) + 8 * (r >> 2);
                OUT[(size_t)grow * 256 + gcol] = (f16)acc[mi][ni][r];
            }
        }
#undef STAGE
#undef COMPUTE
}

// ---------------------------------------------------------------------------
// k_seg: segment mean per (token, batch). grid (2048, 2), block 256.
// (ref multiplies out by mask, then segment-sums with mask weight -> msk^2)
// ---------------------------------------------------------------------------
__global__ __launch_bounds__(256) void k_seg(const f16* __restrict__ OUT,
                                             const int* __restrict__ uid,
                                             const float* __restrict__ mask,
                                             float* __restrict__ out) {
    const int t = blockIdx.x, b = blockIdx.y;
    const int d = threadIdx.x;
    const int* u = uid + b * Mg;

    int lo = 0, hi = Mg;
    while (lo < hi) { int mid = (lo + hi) >> 1; if (u[mid] < t) lo = mid + 1; else hi = mid; }
    int lo2 = lo, hi2 = Mg;
    while (lo2 < hi2) { int mid = (lo2 + hi2) >> 1; if (u[mid] < t + 1) lo2 = mid + 1; else hi2 = mid; }

    float sum = 0.f, cnt = 0.f;
    for (int m = lo; m < lo2; ++m) {
        float msk = mask[b * Mg + m];
        sum += msk * msk * (float)OUT[((size_t)b * Mg + m) * 256 + d];
        cnt += msk;
    }
    out[((size_t)b * Ntok + t) * 256 + d] = sum / (cnt + 1e-8f);
}

// ---------------------------------------------------------------------------
extern "C" void kernel_launch(void* const* d_in, const int* in_sizes, int n_in,
                              void* d_out, int out_size, void* d_ws, size_t ws_size,
                              hipStream_t stream) {
    const float* f_atom = (const float*)d_in[0];
    const float* amask  = (const float*)d_in[1];
    const float* Wq     = (const float*)d_in[2];
    const float* Wk     = (const float*)d_in[3];
    const float* Wv     = (const float*)d_in[4];
    const float* Wo     = (const float*)d_in[5];
    const int*   uid    = (const int*)d_in[6];

    const size_t HALF_WT  = 4 * 65536;
    const size_t HALF_MAT = (size_t)Bg * Mg * Dg;
    const size_t needed_bytes = (HALF_WT + 5 * HALF_MAT) * sizeof(f16);
    if (ws_size < needed_bytes) return;

    f16* Wsw  = (f16*)d_ws;
    f16* Ah   = Wsw + HALF_WT;
    f16* Qb   = Ah + HALF_MAT;
    f16* Kb   = Qb + HALF_MAT;
    f16* VTb  = Kb + HALF_MAT;
    f16* OUTb = VTb + HALF_MAT;
    f16* AOsw = Ah;                  // alias: Ah dead after k_qkv

    k_wt  <<<dim3(1024), 256, 0, stream>>>(Wq, Wk, Wv, Wo, Wsw);
    k_cvt <<<dim3(4096), 256, 0, stream>>>(f_atom, Ah);
    k_qkv <<<dim3(1536), 256, 0, stream>>>(Ah, Wsw, Qb, Kb, VTb);
    k_attn<<<dim3(1024), 512, 0, stream>>>(Qb, Kb, VTb, AOsw);
    k_out <<<dim3(512), 256, 0, stream>>>(AOsw, Wsw, OUTb);
    k_seg <<<dim3(Ntok, Bg), 256, 0, stream>>>(OUTb, uid, amask, (float*)d_out);
}

// Round 4
// 100.357 us; speedup vs baseline: 1.3544x; 1.0251x over previous
//
#include <hip/hip_runtime.h>

typedef _Float16 f16;
typedef _Float16 f16x4 __attribute__((ext_vector_type(4)));
typedef _Float16 f16x8 __attribute__((ext_vector_type(8)));
typedef float    f32x16 __attribute__((ext_vector_type(16)));

#define MFMA(a, b, c) __builtin_amdgcn_mfma_f32_32x32x16_f16((a), (b), (c), 0, 0, 0)

static constexpr int Mg   = 16384;
static constexpr int Bg   = 2;
static constexpr int Dg   = 256;
static constexpr int Hg   = 8;
static constexpr int Cg   = 512;
static constexpr int Ntok = 2048;
static constexpr float QSCALE = 0.17677669529663687f; // 1/sqrt(32)

typedef __attribute__((address_space(1))) const void gbl_cv;
typedef __attribute__((address_space(3))) void lds_v;

static __device__ __forceinline__ void gll16(const f16* g, f16* l) {
    __builtin_amdgcn_global_load_lds((gbl_cv*)g, (lds_v*)l, 16, 0, 0);
}
static __device__ __forceinline__ f16x8 mk8(f16x4 a, f16x4 b) {
    f16x8 r;
    r[0] = a[0]; r[1] = a[1]; r[2] = a[2]; r[3] = a[3];
    r[4] = b[0]; r[5] = b[1]; r[6] = b[2]; r[7] = b[3];
    return r;
}

// ---------------------------------------------------------------------------
// k_wt: W[k][n] fp32 -> Wsw[w][n][k-swizzled] fp16 (slot^(n&7) per 64-col grp)
// ---------------------------------------------------------------------------
__global__ __launch_bounds__(256) void k_wt(const float* __restrict__ Wq,
                                            const float* __restrict__ Wk,
                                            const float* __restrict__ Wv,
                                            const float* __restrict__ Wo,
                                            f16* __restrict__ Wsw) {
    int idx = blockIdx.x * 256 + threadIdx.x;
    int w   = idx >> 16;
    int rem = idx & 65535;
    int k   = rem >> 8;
    int n   = rem & 255;
    const float* W = (w == 0) ? Wq : (w == 1) ? Wk : (w == 2) ? Wv : Wo;
    int k0  = k & ~63;
    int sst = ((k >> 3) & 7) ^ (n & 7);
    Wsw[w * 65536 + n * 256 + k0 + (sst << 3) + (k & 7)] = (f16)W[k * 256 + n];
}

// ---------------------------------------------------------------------------
// k_cvt: A fp32 [32768][256] -> Ah fp16, swizzled (slot^(m&7) per 64-col grp)
// ---------------------------------------------------------------------------
__global__ __launch_bounds__(256) void k_cvt(const float* __restrict__ A,
                                             f16* __restrict__ Ah) {
    int g  = blockIdx.x * 256 + threadIdx.x;
    int m  = g >> 5, sg = g & 31;
    int k0 = (sg >> 3) << 6;
    int sst = (sg & 7) ^ (m & 7);
    const float* src = A + (size_t)m * 256 + sg * 8;
    float4 v0 = *reinterpret_cast<const float4*>(src);
    float4 v1 = *reinterpret_cast<const float4*>(src + 4);
    f16x8 h8 = { (f16)v0.x, (f16)v0.y, (f16)v0.z, (f16)v0.w,
                 (f16)v1.x, (f16)v1.y, (f16)v1.z, (f16)v1.w };
    *reinterpret_cast<f16x8*>(Ah + (size_t)m * 256 + k0 + (sst << 3)) = h8;
}

// ---------------------------------------------------------------------------
// k_qkv: Ah(sw) x Wsw -> Q(scaled), K, VT. 128x128 tile, BK=64, dbuf LDS,
// global_load_lds(16B), T3 minimum-2-phase: STAGE(next)+COMPUTE(cur)+1 barrier.
// grid 1536 (XCD-chunked), 256 thr.
// ---------------------------------------------------------------------------
__global__ __launch_bounds__(256, 2) void k_qkv(const f16* __restrict__ Ah,
                                                const f16* __restrict__ Wsw,
                                                f16* __restrict__ Qo,
                                                f16* __restrict__ Ko,
                                                f16* __restrict__ VT) {
    __shared__ f16 As[2][128 * 64];
    __shared__ f16 Ws[2][128 * 64];

    const int tid = threadIdx.x;
    const int d   = blockIdx.x;
    const int lin = (d & 7) * 192 + (d >> 3);
    const int ytile = lin / 6;
    const int x6    = lin % 6;
    const int wix   = x6 >> 1;
    const int nt    = x6 & 1;
    const int m0 = ytile * 128, n0 = nt * 128;

    const f16* Asrc = Ah + (size_t)m0 * 256;
    const f16* Wsrc = Wsw + wix * 65536 + (size_t)n0 * 256;

    const int lane = tid & 63, wid = tid >> 6;
    const int wm = wid >> 1, wn = wid & 1;
    const int l31 = lane & 31, hi = lane >> 5;
    const int rb7 = l31 & 7;

    f32x16 acc[2][2];
#pragma unroll
    for (int mi = 0; mi < 2; ++mi)
#pragma unroll
        for (int ni = 0; ni < 2; ++ni)
#pragma unroll
            for (int e = 0; e < 16; ++e) acc[mi][ni][e] = 0.f;

#define STAGE(K0, BB)                                                          \
    {                                                                          \
        _Pragma("unroll")                                                      \
        for (int i = 0; i < 4; ++i) {                                          \
            int g = i * 256 + tid;                                             \
            int r = g >> 3, s = g & 7;                                         \
            gll16(Asrc + r * 256 + (K0) + s * 8, &As[BB][g * 8]);              \
            gll16(Wsrc + r * 256 + (K0) + s * 8, &Ws[BB][g * 8]);              \
        }                                                                      \
    }

#define COMPUTE(BB)                                                            \
    {                                                                          \
        _Pragma("unroll")                                                      \
        for (int ks = 0; ks < 4; ++ks) {                                       \
            const int sl = (2 * ks + hi) ^ rb7;                                \
            f16x8 af[2], bf[2];                                                \
            _Pragma("unroll")                                                  \
            for (int mi = 0; mi < 2; ++mi)                                     \
                af[mi] = *(const f16x8*)&As[BB][(wm * 64 + mi * 32 + l31) * 64 + sl * 8]; \
            _Pragma("unroll")                                                  \
            for (int ni = 0; ni < 2; ++ni)                                     \
                bf[ni] = *(const f16x8*)&Ws[BB][(wn * 64 + ni * 32 + l31) * 64 + sl * 8]; \
            _Pragma("unroll")                                                  \
            for (int mi = 0; mi < 2; ++mi)                                     \
                _Pragma("unroll")                                              \
                for (int ni = 0; ni < 2; ++ni)                                 \
                    acc[mi][ni] = MFMA(af[mi], bf[ni], acc[mi][ni]);           \
        }                                                                      \
    }

#define SYNCP()                                                                \
    asm volatile("s_waitcnt vmcnt(0)" ::: "memory");                           \
    __builtin_amdgcn_s_barrier();                                              \
    __builtin_amdgcn_sched_barrier(0);

    STAGE(0, 0);
    SYNCP();
    STAGE(64, 1);
    COMPUTE(0);
    SYNCP();
    STAGE(128, 0);
    COMPUTE(1);
    SYNCP();
    STAGE(192, 1);
    COMPUTE(0);
    SYNCP();
    COMPUTE(1);

#pragma unroll
    for (int mi = 0; mi < 2; ++mi) {
#pragma unroll
        for (int ni = 0; ni < 2; ++ni) {
            const int gcol  = n0 + wn * 64 + ni * 32 + l31;
            const int mbase = m0 + wm * 64 + mi * 32 + 4 * hi;
            if (wix == 0) {
#pragma unroll
                for (int r = 0; r < 16; ++r) {
                    int grow = mbase + (r & 3) + 8 * (r >> 2);
                    Qo[(size_t)grow * 256 + gcol] = (f16)(acc[mi][ni][r] * QSCALE);
                }
            } else if (wix == 1) {
#pragma unroll
                for (int r = 0; r < 16; ++r) {
                    int grow = mbase + (r & 3) + 8 * (r >> 2);
                    Ko[(size_t)grow * 256 + gcol] = (f16)acc[mi][ni][r];
                }
            } else {
#pragma unroll
                for (int rq = 0; rq < 4; ++rq) {
                    f16x4 pv = { (f16)acc[mi][ni][rq * 4 + 0], (f16)acc[mi][ni][rq * 4 + 1],
                                 (f16)acc[mi][ni][rq * 4 + 2], (f16)acc[mi][ni][rq * 4 + 3] };
                    int mrow = mbase + 8 * rq;
                    int bb = mrow >> 14, mm = mrow & 16383;
                    *reinterpret_cast<f16x4*>(VT + (size_t)bb * (256 * 16384) +
                                              (size_t)gcol * 16384 + mm) = pv;
                }
            }
        }
    }
#undef STAGE
#undef COMPUTE
#undef SYNCP
}

// ---------------------------------------------------------------------------
// k_attn v3: one WAVE per (b,c,h). grid 8192 XCD-chunked by c, block 64.
// K,Q direct from global (L2-hot). V staged in private 8KB LDS, seg-major
// [16 segs][32 rows][16B] -> conflict-free ds_read_b64 in PV. No barriers.
// ---------------------------------------------------------------------------
__global__ __launch_bounds__(64) void k_attn(const f16* __restrict__ Qo,
                                             const f16* __restrict__ Ko,
                                             const f16* __restrict__ VT,
                                             f16* __restrict__ AOsw) {
    __shared__ f16 Vs[4096];   // 8 KB

    const int tid = threadIdx.x;
    const int idx = blockIdx.x;
    const int lin = (idx & 7) * 1024 + (idx >> 3);   // contiguous c-range per XCD
    const int h = lin & 7;
    const int c = (lin >> 3) & 511;
    const int b = lin >> 12;
    const int l31 = tid & 31, hi = tid >> 5;

    const int u0 = 32 * c - 48;                       // unclamped window base
    const int e0 = (32 * c + 80 < Mg) ? (32 * c + 80) : Mg;

    // ---- stage V window (8 x gll16), seg-major: granule(seg,r) = m[u0+8seg..+8) of d-row r
    const f16* Vb = VT + (size_t)b * Dg * Mg + (size_t)h * 32 * Mg;
#pragma unroll
    for (int i = 0; i < 8; ++i) {
        int seg = 2 * i + hi;
        int m0s = u0 + 8 * seg;
        if (m0s < 0) m0s = 0;                         // clamped granules masked by P==0
        if (m0s > Mg - 8) m0s = Mg - 8;
        gll16(Vb + (size_t)l31 * Mg + m0s, &Vs[i * 512 + tid * 8]);
    }

    // ---- Q fragments
    const f16* qp = Qo + ((size_t)b * Mg + 32 * c + l31) * 256 + h * 32;
    f16x8 qf0 = *reinterpret_cast<const f16x8*>(qp + 8 * hi);
    f16x8 qf1 = *reinterpret_cast<const f16x8*>(qp + 16 + 8 * hi);

    // ---- QK^T, K direct from global
    f32x16 p4[4];
#pragma unroll
    for (int t = 0; t < 4; ++t)
#pragma unroll
        for (int e = 0; e < 16; ++e) p4[t][e] = 0.f;

#pragma unroll
    for (int t = 0; t < 4; ++t) {
        int grow = u0 + 32 * t + l31;
        int grc  = grow < 0 ? 0 : (grow > Mg - 1 ? Mg - 1 : grow);
        const f16* kp = Ko + ((size_t)b * Mg + grc) * 256 + h * 32;
        f16x8 kf0 = *reinterpret_cast<const f16x8*>(kp + 8 * hi);
        f16x8 kf1 = *reinterpret_cast<const f16x8*>(kp + 16 + 8 * hi);
        p4[t] = MFMA(kf0, qf0, p4[t]);
        p4[t] = MFMA(kf1, qf1, p4[t]);
    }

    // ---- masked in-register softmax; valid key slot kk iff 0 <= u0+kk < e0
    float mx = -3e38f;
#pragma unroll
    for (int t = 0; t < 4; ++t)
#pragma unroll
        for (int r = 0; r < 16; ++r) {
            int gm = u0 + 32 * t + (r & 3) + 8 * (r >> 2) + 4 * hi;
            if (gm >= 0 && gm < e0) mx = fmaxf(mx, p4[t][r]);
        }
    mx = fmaxf(mx, __shfl_xor(mx, 32));

    float sum = 0.f;
#pragma unroll
    for (int t = 0; t < 4; ++t)
#pragma unroll
        for (int r = 0; r < 16; ++r) {
            int gm = u0 + 32 * t + (r & 3) + 8 * (r >> 2) + 4 * hi;
            float ev = (gm >= 0 && gm < e0) ? __expf(p4[t][r] - mx) : 0.f;
            p4[t][r] = ev;
            sum += ev;
        }
    sum += __shfl_xor(sum, 32);
    const float inv = 1.f / sum;
#pragma unroll
    for (int t = 0; t < 4; ++t)
#pragma unroll
        for (int e = 0; e < 16; ++e) p4[t][e] *= inv;

    // ---- V ready (own wave's loads only; LDS is wave-private)
    asm volatile("s_waitcnt vmcnt(0)" ::: "memory");
    __builtin_amdgcn_sched_barrier(0);

    // ---- PV from LDS (conflict-free b64 reads)
    f32x16 o;
#pragma unroll
    for (int e = 0; e < 16; ++e) o[e] = 0.f;

#pragma unroll
    for (int s = 0; s < 8; ++s) {
        f16x8 pa;
#pragma unroll
        for (int e = 0; e < 8; ++e) pa[e] = (f16)(p4[s >> 1][8 * (s & 1) + e]);
        f16x4 v0 = *reinterpret_cast<const f16x4*>(&Vs[(2 * s) * 256 + l31 * 8 + 4 * hi]);
        f16x4 v1 = *reinterpret_cast<const f16x4*>(&Vs[(2 * s + 1) * 256 + l31 * 8 + 4 * hi]);
        o = MFMA(pa, mk8(v0, v1), o);
    }

    // ---- store AO in k_out's swizzled layout
#pragma unroll
    for (int r = 0; r < 16; ++r) {
        int mrow = 32 * c + (r & 3) + 8 * (r >> 2) + 4 * hi;
        int cc   = h * 32 + l31;
        int sl   = ((cc >> 3) & 7) ^ (mrow & 7);
        int cs   = (cc & ~63) | (sl << 3) | (cc & 7);
        AOsw[((size_t)b * Mg + mrow) * 256 + cs] = (f16)o[r];
    }
}

// ---------------------------------------------------------------------------
// k_out: AOsw x Wo -> OUT (plain). grid 512, same T3 schedule as k_qkv.
// ---------------------------------------------------------------------------
__global__ __launch_bounds__(256, 2) void k_out(const f16* __restrict__ AOsw,
                                                const f16* __restrict__ Wsw,
                                                f16* __restrict__ OUT) {
    __shared__ f16 As[2][128 * 64];
    __shared__ f16 Ws[2][128 * 64];

    const int tid = threadIdx.x;
    const int d   = blockIdx.x;
    const int lin = (d & 7) * 64 + (d >> 3);
    const int ytile = lin >> 1;
    const int nt    = lin & 1;
    const int m0 = ytile * 128, n0 = nt * 128;

    const f16* Asrc = AOsw + (size_t)m0 * 256;
    const f16* Wsrc = Wsw + 3 * 65536 + (size_t)n0 * 256;

    const int lane = tid & 63, wid = tid >> 6;
    const int wm = wid >> 1, wn = wid & 1;
    const int l31 = lane & 31, hi = lane >> 5;
    const int rb7 = l31 & 7;

    f32x16 acc[2][2];
#pragma unroll
    for (int mi = 0; mi < 2; ++mi)
#pragma unroll
        for (int ni = 0; ni < 2; ++ni)
#pragma unroll
            for (int e = 0; e < 16; ++e) acc[mi][ni][e] = 0.f;

#define STAGE(K0, BB)                                                          \
    {                                                                          \
        _Pragma("unroll")                                                      \
        for (int i = 0; i < 4; ++i) {                                          \
            int g = i * 256 + tid;                                             \
            int r = g >> 3, s = g & 7;                                         \
            gll16(Asrc + r * 256 + (K0) + s * 8, &As[BB][g * 8]);              \
            gll16(Wsrc + r * 256 + (K0) + s * 8, &Ws[BB][g * 8]);              \
        }                                                                      \
    }

#define COMPUTE(BB)                                                            \
    {                                                                          \
        _Pragma("unroll")                                                      \
        for (int ks = 0; ks < 4; ++ks) {                                       \
            const int sl = (2 * ks + hi) ^ rb7;                                \
            f16x8 af[2], bf[2];                                                \
            _Pragma("unroll")                                                  \
            for (int mi = 0; mi < 2; ++mi)                                     \
                af[mi] = *(const f16x8*)&As[BB][(wm * 64 + mi * 32 + l31) * 64 + sl * 8]; \
            _Pragma("unroll")                                                  \
            for (int ni = 0; ni < 2; ++ni)                                     \
                bf[ni] = *(const f16x8*)&Ws[BB][(wn * 64 + ni * 32 + l31) * 64 + sl * 8]; \
            _Pragma("unroll")                                                  \
            for (int mi = 0; mi < 2; ++mi)                                     \
                _Pragma("unroll")                                              \
                for (int ni = 0; ni < 2; ++ni)                                 \
                    acc[mi][ni] = MFMA(af[mi], bf[ni], acc[mi][ni]);           \
        }                                                                      \
    }

#define SYNCP()                                                                \
    asm volatile("s_waitcnt vmcnt(0)" ::: "memory");                           \
    __builtin_amdgcn_s_barrier();                                              \
    __builtin_amdgcn_sched_barrier(0);

    STAGE(0, 0);
    SYNCP();
    STAGE(64, 1);
    COMPUTE(0);
    SYNCP();
    STAGE(128, 0);
    COMPUTE(1);
    SYNCP();
    STAGE(192, 1);
    COMPUTE(0);
    SYNCP();
    COMPUTE(1);

#pragma unroll
    for (int mi = 0; mi < 2; ++mi)
#pragma unroll
        for (int ni = 0; ni < 2; ++ni) {
            const int gcol  = n0 + wn * 64 + ni * 32 + l31;
            const int mbase = m0 + wm * 64 + mi * 32 + 4 * hi;
#pragma unroll
            for (int r = 0; r < 16; ++r) {
                int grow = mbase + (r & 3) + 8 * (r >> 2);
                OUT[(size_t)grow * 256 + gcol] = (f16)acc[mi][ni][r];
            }
        }
#undef STAGE
#undef COMPUTE
#undef SYNCP
}

// ---------------------------------------------------------------------------
// k_seg: segment mean per (token, batch). grid (2048, 2), block 256.
// (ref: out*=mask, then segment-sum weighted by mask -> msk^2 on OUT)
// ---------------------------------------------------------------------------
__global__ __launch_bounds__(256) void k_seg(const f16* __restrict__ OUT,
                                             const int* __restrict__ uid,
                                             const float* __restrict__ mask,
                                             float* __restrict__ out) {
    const int t = blockIdx.x, b = blockIdx.y;
    const int d = threadIdx.x;
    const int* u = uid + b * Mg;

    int lo = 0, hi = Mg;
    while (lo < hi) { int mid = (lo + hi) >> 1; if (u[mid] < t) lo = mid + 1; else hi = mid; }
    int lo2 = lo, hi2 = Mg;
    while (lo2 < hi2) { int mid = (lo2 + hi2) >> 1; if (u[mid] < t + 1) lo2 = mid + 1; else hi2 = mid; }

    float sum = 0.f, cnt = 0.f;
    for (int m = lo; m < lo2; ++m) {
        float msk = mask[b * Mg + m];
        sum += msk * msk * (float)OUT[((size_t)b * Mg + m) * 256 + d];
        cnt += msk;
    }
    out[((size_t)b * Ntok + t) * 256 + d] = sum / (cnt + 1e-8f);
}

// ---------------------------------------------------------------------------
extern "C" void kernel_launch(void* const* d_in, const int* in_sizes, int n_in,
                              void* d_out, int out_size, void* d_ws, size_t ws_size,
                              hipStream_t stream) {
    const float* f_atom = (const float*)d_in[0];
    const float* amask  = (const float*)d_in[1];
    const float* Wq     = (const float*)d_in[2];
    const float* Wk     = (const float*)d_in[3];
    const float* Wv     = (const float*)d_in[4];
    const float* Wo     = (const float*)d_in[5];
    const int*   uid    = (const int*)d_in[6];

    const size_t HALF_WT  = 4 * 65536;
    const size_t HALF_MAT = (size_t)Bg * Mg * Dg;
    const size_t needed_bytes = (HALF_WT + 5 * HALF_MAT) * sizeof(f16);
    if (ws_size < needed_bytes) return;

    f16* Wsw  = (f16*)d_ws;
    f16* Ah   = Wsw + HALF_WT;
    f16* Qb   = Ah + HALF_MAT;
    f16* Kb   = Qb + HALF_MAT;
    f16* VTb  = Kb + HALF_MAT;
    f16* OUTb = VTb + HALF_MAT;
    f16* AOsw = Ah;                  // alias: Ah dead after k_qkv

    k_wt  <<<dim3(1024), 256, 0, stream>>>(Wq, Wk, Wv, Wo, Wsw);
    k_cvt <<<dim3(4096), 256, 0, stream>>>(f_atom, Ah);
    k_qkv <<<dim3(1536), 256, 0, stream>>>(Ah, Wsw, Qb, Kb, VTb);
    k_attn<<<dim3(8192), 64, 0, stream>>>(Qb, Kb, VTb, AOsw);
    k_out <<<dim3(512), 256, 0, stream>>>(AOsw, Wsw, OUTb);
    k_seg <<<dim3(Ntok, Bg), 256, 0, stream>>>(OUTb, uid, amask, (float*)d_out);
}

// Round 6
// 91.071 us; speedup vs baseline: 1.4925x; 1.1020x over previous
//
#include <hip/hip_runtime.h>

typedef _Float16 f16;
typedef _Float16 f16x4 __attribute__((ext_vector_type(4)));
typedef _Float16 f16x8 __attribute__((ext_vector_type(8)));
typedef float    f32x16 __attribute__((ext_vector_type(16)));

#define MFMA(a, b, c) __builtin_amdgcn_mfma_f32_32x32x16_f16((a), (b), (c), 0, 0, 0)

static constexpr int Mg   = 16384;
static constexpr int Bg   = 2;
static constexpr int Dg   = 256;
static constexpr int Hg   = 8;
static constexpr int Cg   = 512;
static constexpr int Ntok = 2048;
static constexpr float QSCALE = 0.17677669529663687f; // 1/sqrt(32)

typedef __attribute__((address_space(1))) const void gbl_cv;
typedef __attribute__((address_space(3))) void lds_v;

static __device__ __forceinline__ void gll16(const f16* g, f16* l) {
    __builtin_amdgcn_global_load_lds((gbl_cv*)g, (lds_v*)l, 16, 0, 0);
}
static __device__ __forceinline__ f16x8 mk8(f16x4 a, f16x4 b) {
    f16x8 r;
    r[0] = a[0]; r[1] = a[1]; r[2] = a[2]; r[3] = a[3];
    r[4] = b[0]; r[5] = b[1]; r[6] = b[2]; r[7] = b[3];
    return r;
}

// ---------------------------------------------------------------------------
// k_wt: W[k][n] fp32 -> Wsw[w][n][granule (k>>3)^(n&7)] fp16.
// Granule-XOR over the whole 256-k row: staging is a LINEAR copy, LDS read
// applies the same XOR -> bounded bank conflicts.
// ---------------------------------------------------------------------------
__global__ __launch_bounds__(256) void k_wt(const float* __restrict__ Wq,
                                            const float* __restrict__ Wk,
                                            const float* __restrict__ Wv,
                                            const float* __restrict__ Wo,
                                            f16* __restrict__ Wsw) {
    int idx = blockIdx.x * 256 + threadIdx.x;
    int w   = idx >> 16;
    int rem = idx & 65535;
    int k   = rem >> 8;
    int n   = rem & 255;
    const float* W = (w == 0) ? Wq : (w == 1) ? Wk : (w == 2) ? Wv : Wo;
    int G = (k >> 3) ^ (n & 7);
    Wsw[w * 65536 + n * 256 + (G << 3) + (k & 7)] = (f16)W[k * 256 + n];
}

// ---------------------------------------------------------------------------
// k_qkv v3: A-in-registers GEMM. 512 blocks = (ytile 0..255) x (half 0..1),
// 256 thr / 4 waves; wave owns 32 rows. A (fp32) loaded once -> 64 VGPR fp16.
// 12 column-steps of 32 (spanning Q,K,V), W streamed via dbuf LDS gll16.
// Counted vmcnt = #stores issued this step (16 for Q/K, 4 for V) so the wait
// drains exactly [leftover stores + 4 staging loads] -- the V-step race fix.
// ---------------------------------------------------------------------------
__global__ __launch_bounds__(256, 2) void k_qkv(const float* __restrict__ A,
                                                const f16* __restrict__ Wsw,
                                                f16* __restrict__ Qo,
                                                f16* __restrict__ Ko,
                                                f16* __restrict__ VT) {
    __shared__ f16 Ls[2][32 * 256];   // 2 x 16 KB

    const int tid  = threadIdx.x;
    const int d    = blockIdx.x;
    const int lin  = (d & 7) * 64 + (d >> 3);   // ytile-pairs adjacent per XCD
    const int yt   = lin >> 1;
    const int half = lin & 1;
    const int m0   = yt * 128;
    const int lane = tid & 63, w = tid >> 6;
    const int l31  = lane & 31, hi = lane >> 5;
    const int mrow = m0 + 32 * w + l31;
    const int xr   = l31 & 7;

    // ---- A rows -> registers (fp32 -> fp16), k = 16g + 8hi + e
    f16x8 a[16];
    const float* ap = A + (size_t)mrow * 256 + 8 * hi;
#pragma unroll
    for (int g = 0; g < 16; ++g) {
        float4 v0 = *reinterpret_cast<const float4*>(ap + 16 * g);
        float4 v1 = *reinterpret_cast<const float4*>(ap + 16 * g + 4);
        f16x8 t;
        t[0] = (f16)v0.x; t[1] = (f16)v0.y; t[2] = (f16)v0.z; t[3] = (f16)v0.w;
        t[4] = (f16)v1.x; t[5] = (f16)v1.y; t[6] = (f16)v1.z; t[7] = (f16)v1.w;
        a[g] = t;
    }

#define STW(S, BB)                                                             \
    {                                                                          \
        const f16* src = Wsw + ((S) >> 3) * 65536 + (((S) & 7) * 32) * 256;    \
        _Pragma("unroll")                                                      \
        for (int i = 0; i < 4; ++i) {                                          \
            int g2 = i * 256 + tid;                                            \
            gll16(src + g2 * 8, &Ls[BB][g2 * 8]);                              \
        }                                                                      \
    }

#define QKV_STEP(S, BB)                                                        \
    {                                                                          \
        if ((S) + 1 < s_end) { STW((S) + 1, (BB) ^ 1); }                       \
        f32x16 acc;                                                            \
        _Pragma("unroll")                                                      \
        for (int e = 0; e < 16; ++e) acc[e] = 0.f;                             \
        _Pragma("unroll")                                                      \
        for (int g = 0; g < 16; ++g) {                                         \
            f16x8 bf = *(const f16x8*)&Ls[BB][l31 * 256 +                      \
                                             (((2 * g + hi) ^ xr) << 3)];      \
            acc = MFMA(a[g], bf, acc);                                         \
        }                                                                      \
        const int wix  = (S) >> 3;                                             \
        const int gcol = ((S) & 7) * 32 + l31;                                 \
        const int mb   = m0 + 32 * w + 4 * hi;                                 \
        if (wix == 0) {                                                        \
            _Pragma("unroll")                                                  \
            for (int r = 0; r < 16; ++r)                                       \
                Qo[(size_t)(mb + (r & 3) + 8 * (r >> 2)) * 256 + gcol] =       \
                    (f16)(acc[r] * QSCALE);                                    \
        } else if (wix == 1) {                                                 \
            _Pragma("unroll")                                                  \
            for (int r = 0; r < 16; ++r)                                       \
                Ko[(size_t)(mb + (r & 3) + 8 * (r >> 2)) * 256 + gcol] =       \
                    (f16)acc[r];                                               \
        } else {                                                               \
            _Pragma("unroll")                                                  \
            for (int rq = 0; rq < 4; ++rq) {                                   \
                f16x4 pv = { (f16)acc[rq * 4 + 0], (f16)acc[rq * 4 + 1],       \
                             (f16)acc[rq * 4 + 2], (f16)acc[rq * 4 + 3] };     \
                int mr = mb + 8 * rq;                                          \
                int bb2 = mr >> 14, mm = mr & 16383;                           \
                *reinterpret_cast<f16x4*>(VT + (size_t)bb2 * (256 * 16384) +   \
                                          (size_t)gcol * 16384 + mm) = pv;     \
            }                                                                  \
        }                                                                      \
        if ((S) + 1 < s_end) {                                                 \
            if (((S) >> 3) == 2) {                                             \
                asm volatile("s_waitcnt vmcnt(4)" ::: "memory");               \
            } else {                                                           \
                asm volatile("s_waitcnt vmcnt(16)" ::: "memory");              \
            }                                                                  \
            __builtin_amdgcn_s_barrier();                                      \
            __builtin_amdgcn_sched_barrier(0);                                 \
        }                                                                      \
    }

#define QKV_RUN(BASE)                                                          \
    {                                                                          \
        const int s_end = (BASE) + 12;                                         \
        STW(BASE, 0);                                                          \
        asm volatile("s_waitcnt vmcnt(0)" ::: "memory");                       \
        __builtin_amdgcn_s_barrier();                                          \
        __builtin_amdgcn_sched_barrier(0);                                     \
        _Pragma("unroll")                                                      \
        for (int ss = 0; ss < 12; ++ss) { QKV_STEP((BASE) + ss, ss & 1); }     \
    }

    if (half == 0) { QKV_RUN(0); } else { QKV_RUN(12); }
#undef QKV_RUN
#undef QKV_STEP
#undef STW
}

// ---------------------------------------------------------------------------
// k_attn v3: one WAVE per (b,c,h). grid 8192 XCD-chunked by c, block 64.
// K,Q direct from global (L2-hot). V staged in private 8KB LDS, seg-major.
// AO stored PLAIN (k_out reads it into registers directly).
// ---------------------------------------------------------------------------
__global__ __launch_bounds__(64) void k_attn(const f16* __restrict__ Qo,
                                             const f16* __restrict__ Ko,
                                             const f16* __restrict__ VT,
                                             f16* __restrict__ AO) {
    __shared__ f16 Vs[4096];   // 8 KB

    const int tid = threadIdx.x;
    const int idx = blockIdx.x;
    const int lin = (idx & 7) * 1024 + (idx >> 3);
    const int h = lin & 7;
    const int c = (lin >> 3) & 511;
    const int b = lin >> 12;
    const int l31 = tid & 31, hi = tid >> 5;

    const int u0 = 32 * c - 48;
    const int e0 = (32 * c + 80 < Mg) ? (32 * c + 80) : Mg;

    const f16* Vb = VT + (size_t)b * Dg * Mg + (size_t)h * 32 * Mg;
#pragma unroll
    for (int i = 0; i < 8; ++i) {
        int seg = 2 * i + hi;
        int m0s = u0 + 8 * seg;
        if (m0s < 0) m0s = 0;
        if (m0s > Mg - 8) m0s = Mg - 8;
        gll16(Vb + (size_t)l31 * Mg + m0s, &Vs[i * 512 + tid * 8]);
    }

    const f16* qp = Qo + ((size_t)b * Mg + 32 * c + l31) * 256 + h * 32;
    f16x8 qf0 = *reinterpret_cast<const f16x8*>(qp + 8 * hi);
    f16x8 qf1 = *reinterpret_cast<const f16x8*>(qp + 16 + 8 * hi);

    f32x16 p4[4];
#pragma unroll
    for (int t = 0; t < 4; ++t)
#pragma unroll
        for (int e = 0; e < 16; ++e) p4[t][e] = 0.f;

#pragma unroll
    for (int t = 0; t < 4; ++t) {
        int grow = u0 + 32 * t + l31;
        int grc  = grow < 0 ? 0 : (grow > Mg - 1 ? Mg - 1 : grow);
        const f16* kp = Ko + ((size_t)b * Mg + grc) * 256 + h * 32;
        f16x8 kf0 = *reinterpret_cast<const f16x8*>(kp + 8 * hi);
        f16x8 kf1 = *reinterpret_cast<const f16x8*>(kp + 16 + 8 * hi);
        p4[t] = MFMA(kf0, qf0, p4[t]);
        p4[t] = MFMA(kf1, qf1, p4[t]);
    }

    float mx = -3e38f;
#pragma unroll
    for (int t = 0; t < 4; ++t)
#pragma unroll
        for (int r = 0; r < 16; ++r) {
            int gm = u0 + 32 * t + (r & 3) + 8 * (r >> 2) + 4 * hi;
            if (gm >= 0 && gm < e0) mx = fmaxf(mx, p4[t][r]);
        }
    mx = fmaxf(mx, __shfl_xor(mx, 32));

    float sum = 0.f;
#pragma unroll
    for (int t = 0; t < 4; ++t)
#pragma unroll
        for (int r = 0; r < 16; ++r) {
            int gm = u0 + 32 * t + (r & 3) + 8 * (r >> 2) + 4 * hi;
            float ev = (gm >= 0 && gm < e0) ? __expf(p4[t][r] - mx) : 0.f;
            p4[t][r] = ev;
            sum += ev;
        }
    sum += __shfl_xor(sum, 32);
    const float inv = 1.f / sum;
#pragma unroll
    for (int t = 0; t < 4; ++t)
#pragma unroll
        for (int e = 0; e < 16; ++e) p4[t][e] *= inv;

    asm volatile("s_waitcnt vmcnt(0)" ::: "memory");
    __builtin_amdgcn_sched_barrier(0);

    f32x16 o;
#pragma unroll
    for (int e = 0; e < 16; ++e) o[e] = 0.f;

#pragma unroll
    for (int s = 0; s < 8; ++s) {
        f16x8 pa;
#pragma unroll
        for (int e = 0; e < 8; ++e) pa[e] = (f16)(p4[s >> 1][8 * (s & 1) + e]);
        f16x4 v0 = *reinterpret_cast<const f16x4*>(&Vs[(2 * s) * 256 + l31 * 8 + 4 * hi]);
        f16x4 v1 = *reinterpret_cast<const f16x4*>(&Vs[(2 * s + 1) * 256 + l31 * 8 + 4 * hi]);
        o = MFMA(pa, mk8(v0, v1), o);
    }

#pragma unroll
    for (int r = 0; r < 16; ++r) {
        int mrow = 32 * c + (r & 3) + 8 * (r >> 2) + 4 * hi;
        AO[((size_t)b * Mg + mrow) * 256 + h * 32 + l31] = (f16)o[r];
    }
}

// ---------------------------------------------------------------------------
// k_out v2: same A-in-registers structure. 512 blocks, 4 column-steps each.
// A = AO (fp16, plain), W = Wsw[3]. All steps issue 16 stores -> vmcnt(16) ok.
// ---------------------------------------------------------------------------
__global__ __launch_bounds__(256, 2) void k_out(const f16* __restrict__ AO,
                                                const f16* __restrict__ Wsw,
                                                f16* __restrict__ OUT) {
    __shared__ f16 Ls[2][32 * 256];

    const int tid  = threadIdx.x;
    const int d    = blockIdx.x;
    const int lin  = (d & 7) * 64 + (d >> 3);
    const int yt   = lin >> 1;
    const int half = lin & 1;
    const int m0   = yt * 128;
    const int lane = tid & 63, w = tid >> 6;
    const int l31  = lane & 31, hi = lane >> 5;
    const int mrow = m0 + 32 * w + l31;
    const int xr   = l31 & 7;

    f16x8 a[16];
    const f16* ap = AO + (size_t)mrow * 256 + 8 * hi;
#pragma unroll
    for (int g = 0; g < 16; ++g)
        a[g] = *reinterpret_cast<const f16x8*>(ap + 16 * g);

#define STW(S, BB)                                                             \
    {                                                                          \
        const f16* src = Wsw + 3 * 65536 + ((S) * 32) * 256;                   \
        _Pragma("unroll")                                                      \
        for (int i = 0; i < 4; ++i) {                                          \
            int g2 = i * 256 + tid;                                            \
            gll16(src + g2 * 8, &Ls[BB][g2 * 8]);                              \
        }                                                                      \
    }

    const int s_base = half * 4;
    STW(s_base, 0);
    asm volatile("s_waitcnt vmcnt(0)" ::: "memory");
    __builtin_amdgcn_s_barrier();
    __builtin_amdgcn_sched_barrier(0);

#pragma unroll
    for (int ss = 0; ss < 4; ++ss) {
        const int S  = s_base + ss;
        const int BB = ss & 1;
        if (ss + 1 < 4) { STW(S + 1, BB ^ 1); }
        f32x16 acc;
#pragma unroll
        for (int e = 0; e < 16; ++e) acc[e] = 0.f;
#pragma unroll
        for (int g = 0; g < 16; ++g) {
            f16x8 bf = *(const f16x8*)&Ls[BB][l31 * 256 + (((2 * g + hi) ^ xr) << 3)];
            acc = MFMA(a[g], bf, acc);
        }
        const int gcol = S * 32 + l31;
        const int mb   = m0 + 32 * w + 4 * hi;
#pragma unroll
        for (int r = 0; r < 16; ++r)
            OUT[(size_t)(mb + (r & 3) + 8 * (r >> 2)) * 256 + gcol] = (f16)acc[r];
        if (ss + 1 < 4) {
            asm volatile("s_waitcnt vmcnt(16)" ::: "memory");
            __builtin_amdgcn_s_barrier();
            __builtin_amdgcn_sched_barrier(0);
        }
    }
#undef STW
}

// ---------------------------------------------------------------------------
// k_seg: segment mean per (token, batch). grid (2048, 2), block 256.
// (ref: out*=mask, then segment-sum weighted by mask -> msk^2 on OUT)
// ---------------------------------------------------------------------------
__global__ __launch_bounds__(256) void k_seg(const f16* __restrict__ OUT,
                                             const int* __restrict__ uid,
                                             const float* __restrict__ mask,
                                             float* __restrict__ out) {
    const int t = blockIdx.x, b = blockIdx.y;
    const int d = threadIdx.x;
    const int* u = uid + b * Mg;

    int lo = 0, hi = Mg;
    while (lo < hi) { int mid = (lo + hi) >> 1; if (u[mid] < t) lo = mid + 1; else hi = mid; }
    int lo2 = lo, hi2 = Mg;
    while (lo2 < hi2) { int mid = (lo2 + hi2) >> 1; if (u[mid] < t + 1) lo2 = mid + 1; else hi2 = mid; }

    float sum = 0.f, cnt = 0.f;
    for (int m = lo; m < lo2; ++m) {
        float msk = mask[b * Mg + m];
        sum += msk * msk * (float)OUT[((size_t)b * Mg + m) * 256 + d];
        cnt += msk;
    }
    out[((size_t)b * Ntok + t) * 256 + d] = sum / (cnt + 1e-8f);
}

// ---------------------------------------------------------------------------
extern "C" void kernel_launch(void* const* d_in, const int* in_sizes, int n_in,
                              void* d_out, int out_size, void* d_ws, size_t ws_size,
                              hipStream_t stream) {
    const float* f_atom = (const float*)d_in[0];
    const float* amask  = (const float*)d_in[1];
    const float* Wq     = (const float*)d_in[2];
    const float* Wk     = (const float*)d_in[3];
    const float* Wv     = (const float*)d_in[4];
    const float* Wo     = (const float*)d_in[5];
    const int*   uid    = (const int*)d_in[6];

    const size_t HALF_WT  = 4 * 65536;
    const size_t HALF_MAT = (size_t)Bg * Mg * Dg;
    const size_t needed_bytes = (HALF_WT + 5 * HALF_MAT) * sizeof(f16);
    if (ws_size < needed_bytes) return;

    f16* Wsw  = (f16*)d_ws;
    f16* Qb   = Wsw + HALF_WT;
    f16* Kb   = Qb + HALF_MAT;
    f16* VTb  = Kb + HALF_MAT;
    f16* AOb  = VTb + HALF_MAT;
    f16* OUTb = AOb + HALF_MAT;

    k_wt  <<<dim3(1024), 256, 0, stream>>>(Wq, Wk, Wv, Wo, Wsw);
    k_qkv <<<dim3(512), 256, 0, stream>>>(f_atom, Wsw, Qb, Kb, VTb);
    k_attn<<<dim3(8192), 64, 0, stream>>>(Qb, Kb, VTb, AOb);
    k_out <<<dim3(512), 256, 0, stream>>>(AOb, Wsw, OUTb);
    k_seg <<<dim3(Ntok, Bg), 256, 0, stream>>>(OUTb, uid, amask, (float*)d_out);
}

// Round 7
// 88.347 us; speedup vs baseline: 1.5385x; 1.0308x over previous
//
#include <hip/hip_runtime.h>

typedef _Float16 f16;
typedef _Float16 f16x4 __attribute__((ext_vector_type(4)));
typedef _Float16 f16x8 __attribute__((ext_vector_type(8)));
typedef float    f32x16 __attribute__((ext_vector_type(16)));

#define MFMA(a, b, c) __builtin_amdgcn_mfma_f32_32x32x16_f16((a), (b), (c), 0, 0, 0)

static constexpr int Mg   = 16384;
static constexpr int Bg   = 2;
static constexpr int Dg   = 256;
static constexpr int Hg   = 8;
static constexpr int Cg   = 512;
static constexpr int Ntok = 2048;
static constexpr float QSCALE = 0.17677669529663687f; // 1/sqrt(32)

typedef __attribute__((address_space(1))) const void gbl_cv;
typedef __attribute__((address_space(3))) void lds_v;

static __device__ __forceinline__ void gll16(const f16* g, f16* l) {
    __builtin_amdgcn_global_load_lds((gbl_cv*)g, (lds_v*)l, 16, 0, 0);
}
static __device__ __forceinline__ f16x8 mk8(f16x4 a, f16x4 b) {
    f16x8 r;
    r[0] = a[0]; r[1] = a[1]; r[2] = a[2]; r[3] = a[3];
    r[4] = b[0]; r[5] = b[1]; r[6] = b[2]; r[7] = b[3];
    return r;
}

// ---------------------------------------------------------------------------
// k_wt: W[k][n] fp32 -> Wsw[w][n][granule (k>>3)^(n&7)] fp16.
// ---------------------------------------------------------------------------
__global__ __launch_bounds__(256) void k_wt(const float* __restrict__ Wq,
                                            const float* __restrict__ Wk,
                                            const float* __restrict__ Wv,
                                            const float* __restrict__ Wo,
                                            f16* __restrict__ Wsw) {
    int idx = blockIdx.x * 256 + threadIdx.x;
    int w   = idx >> 16;
    int rem = idx & 65535;
    int k   = rem >> 8;
    int n   = rem & 255;
    const float* W = (w == 0) ? Wq : (w == 1) ? Wk : (w == 2) ? Wv : Wo;
    int G = (k >> 3) ^ (n & 7);
    Wsw[w * 65536 + n * 256 + (G << 3) + (k & 7)] = (f16)W[k * 256 + n];
}

// ---------------------------------------------------------------------------
// k_qkv: A-in-registers GEMM (validated R6). 512 blocks, 4 waves, 12 steps.
// ---------------------------------------------------------------------------
__global__ __launch_bounds__(256, 2) void k_qkv(const float* __restrict__ A,
                                                const f16* __restrict__ Wsw,
                                                f16* __restrict__ Qo,
                                                f16* __restrict__ Ko,
                                                f16* __restrict__ VT) {
    __shared__ f16 Ls[2][32 * 256];   // 2 x 16 KB

    const int tid  = threadIdx.x;
    const int d    = blockIdx.x;
    const int lin  = (d & 7) * 64 + (d >> 3);
    const int yt   = lin >> 1;
    const int half = lin & 1;
    const int m0   = yt * 128;
    const int lane = tid & 63, w = tid >> 6;
    const int l31  = lane & 31, hi = lane >> 5;
    const int mrow = m0 + 32 * w + l31;
    const int xr   = l31 & 7;

    f16x8 a[16];
    const float* ap = A + (size_t)mrow * 256 + 8 * hi;
#pragma unroll
    for (int g = 0; g < 16; ++g) {
        float4 v0 = *reinterpret_cast<const float4*>(ap + 16 * g);
        float4 v1 = *reinterpret_cast<const float4*>(ap + 16 * g + 4);
        f16x8 t;
        t[0] = (f16)v0.x; t[1] = (f16)v0.y; t[2] = (f16)v0.z; t[3] = (f16)v0.w;
        t[4] = (f16)v1.x; t[5] = (f16)v1.y; t[6] = (f16)v1.z; t[7] = (f16)v1.w;
        a[g] = t;
    }

#define STW(S, BB)                                                             \
    {                                                                          \
        const f16* src = Wsw + ((S) >> 3) * 65536 + (((S) & 7) * 32) * 256;    \
        _Pragma("unroll")                                                      \
        for (int i = 0; i < 4; ++i) {                                          \
            int g2 = i * 256 + tid;                                            \
            gll16(src + g2 * 8, &Ls[BB][g2 * 8]);                              \
        }                                                                      \
    }

#define QKV_STEP(S, BB)                                                        \
    {                                                                          \
        if ((S) + 1 < s_end) { STW((S) + 1, (BB) ^ 1); }                       \
        f32x16 acc;                                                            \
        _Pragma("unroll")                                                      \
        for (int e = 0; e < 16; ++e) acc[e] = 0.f;                             \
        _Pragma("unroll")                                                      \
        for (int g = 0; g < 16; ++g) {                                         \
            f16x8 bf = *(const f16x8*)&Ls[BB][l31 * 256 +                      \
                                             (((2 * g + hi) ^ xr) << 3)];      \
            acc = MFMA(a[g], bf, acc);                                         \
        }                                                                      \
        const int wix  = (S) >> 3;                                             \
        const int gcol = ((S) & 7) * 32 + l31;                                 \
        const int mb   = m0 + 32 * w + 4 * hi;                                 \
        if (wix == 0) {                                                        \
            _Pragma("unroll")                                                  \
            for (int r = 0; r < 16; ++r)                                       \
                Qo[(size_t)(mb + (r & 3) + 8 * (r >> 2)) * 256 + gcol] =       \
                    (f16)(acc[r] * QSCALE);                                    \
        } else if (wix == 1) {                                                 \
            _Pragma("unroll")                                                  \
            for (int r = 0; r < 16; ++r)                                       \
                Ko[(size_t)(mb + (r & 3) + 8 * (r >> 2)) * 256 + gcol] =       \
                    (f16)acc[r];                                               \
        } else {                                                               \
            _Pragma("unroll")                                                  \
            for (int rq = 0; rq < 4; ++rq) {                                   \
                f16x4 pv = { (f16)acc[rq * 4 + 0], (f16)acc[rq * 4 + 1],       \
                             (f16)acc[rq * 4 + 2], (f16)acc[rq * 4 + 3] };     \
                int mr = mb + 8 * rq;                                          \
                int bb2 = mr >> 14, mm = mr & 16383;                           \
                *reinterpret_cast<f16x4*>(VT + (size_t)bb2 * (256 * 16384) +   \
                                          (size_t)gcol * 16384 + mm) = pv;     \
            }                                                                  \
        }                                                                      \
        if ((S) + 1 < s_end) {                                                 \
            if (((S) >> 3) == 2) {                                             \
                asm volatile("s_waitcnt vmcnt(4)" ::: "memory");               \
            } else {                                                           \
                asm volatile("s_waitcnt vmcnt(16)" ::: "memory");              \
            }                                                                  \
            __builtin_amdgcn_s_barrier();                                      \
            __builtin_amdgcn_sched_barrier(0);                                 \
        }                                                                      \
    }

#define QKV_RUN(BASE)                                                          \
    {                                                                          \
        const int s_end = (BASE) + 12;                                         \
        STW(BASE, 0);                                                          \
        asm volatile("s_waitcnt vmcnt(0)" ::: "memory");                       \
        __builtin_amdgcn_s_barrier();                                          \
        __builtin_amdgcn_sched_barrier(0);                                     \
        _Pragma("unroll")                                                      \
        for (int ss = 0; ss < 12; ++ss) { QKV_STEP((BASE) + ss, ss & 1); }     \
    }

    if (half == 0) { QKV_RUN(0); } else { QKV_RUN(12); }
#undef QKV_RUN
#undef QKV_STEP
#undef STW
}

// ---------------------------------------------------------------------------
// k_attn (fused attention + output projection). One 512-thr block per (b,c);
// wave h = head h. Phase 1: per-wave attention (private V LDS slice, K/Q
// direct from L2, in-register softmax) -- unchanged from validated R6 code.
// Phase 2: O-tile -> swizzled LDS, barrier, OUT[:,32h:32h+32] = AO x Wo with
// A from LDS (granule-XOR b128 reads), B from L2-resident Wsw[3].
// grid 1024 XCD-chunked; LDS 80 KB -> 2 blocks/CU.
// ---------------------------------------------------------------------------
__global__ __launch_bounds__(512, 4) void k_attn(const f16* __restrict__ Qo,
                                                 const f16* __restrict__ Ko,
                                                 const f16* __restrict__ VT,
                                                 const f16* __restrict__ Wsw,
                                                 f16* __restrict__ OUT) {
    __shared__ f16 Vs[8 * 4096];    // 64 KB: per-wave private 8 KB slices
    __shared__ f16 AOs[32 * 256];   // 16 KB: swizzled AO tile

    const int tid  = threadIdx.x;
    const int idx  = blockIdx.x;
    const int lin  = (idx & 7) * 128 + (idx >> 3);   // contiguous (b,c) per XCD
    const int b    = lin >> 9;
    const int c    = lin & 511;
    const int h    = tid >> 6;
    const int lane = tid & 63;
    const int l31  = lane & 31, hi = lane >> 5;

    const int u0 = 32 * c - 48;
    const int e0 = (32 * c + 80 < Mg) ? (32 * c + 80) : Mg;

    // ---- stage this wave's V window into its private LDS slice
    f16* Vw = Vs + h * 4096;
    const f16* Vb = VT + (size_t)b * Dg * Mg + (size_t)h * 32 * Mg;
#pragma unroll
    for (int i = 0; i < 8; ++i) {
        int seg = 2 * i + hi;
        int m0s = u0 + 8 * seg;
        if (m0s < 0) m0s = 0;
        if (m0s > Mg - 8) m0s = Mg - 8;
        gll16(Vb + (size_t)l31 * Mg + m0s, &Vw[i * 512 + lane * 8]);
    }

    // ---- Q fragments
    const f16* qp = Qo + ((size_t)b * Mg + 32 * c + l31) * 256 + h * 32;
    f16x8 qf0 = *reinterpret_cast<const f16x8*>(qp + 8 * hi);
    f16x8 qf1 = *reinterpret_cast<const f16x8*>(qp + 16 + 8 * hi);

    // ---- QK^T, K direct from global (L2-hot)
    f32x16 p4[4];
#pragma unroll
    for (int t = 0; t < 4; ++t)
#pragma unroll
        for (int e = 0; e < 16; ++e) p4[t][e] = 0.f;

#pragma unroll
    for (int t = 0; t < 4; ++t) {
        int grow = u0 + 32 * t + l31;
        int grc  = grow < 0 ? 0 : (grow > Mg - 1 ? Mg - 1 : grow);
        const f16* kp = Ko + ((size_t)b * Mg + grc) * 256 + h * 32;
        f16x8 kf0 = *reinterpret_cast<const f16x8*>(kp + 8 * hi);
        f16x8 kf1 = *reinterpret_cast<const f16x8*>(kp + 16 + 8 * hi);
        p4[t] = MFMA(kf0, qf0, p4[t]);
        p4[t] = MFMA(kf1, qf1, p4[t]);
    }

    // ---- masked in-register softmax
    float mx = -3e38f;
#pragma unroll
    for (int t = 0; t < 4; ++t)
#pragma unroll
        for (int r = 0; r < 16; ++r) {
            int gm = u0 + 32 * t + (r & 3) + 8 * (r >> 2) + 4 * hi;
            if (gm >= 0 && gm < e0) mx = fmaxf(mx, p4[t][r]);
        }
    mx = fmaxf(mx, __shfl_xor(mx, 32));

    float sum = 0.f;
#pragma unroll
    for (int t = 0; t < 4; ++t)
#pragma unroll
        for (int r = 0; r < 16; ++r) {
            int gm = u0 + 32 * t + (r & 3) + 8 * (r >> 2) + 4 * hi;
            float ev = (gm >= 0 && gm < e0) ? __expf(p4[t][r] - mx) : 0.f;
            p4[t][r] = ev;
            sum += ev;
        }
    sum += __shfl_xor(sum, 32);
    const float inv = 1.f / sum;
#pragma unroll
    for (int t = 0; t < 4; ++t)
#pragma unroll
        for (int e = 0; e < 16; ++e) p4[t][e] *= inv;

    // ---- own V ready (vmcnt is per-wave; LDS slice is wave-private)
    asm volatile("s_waitcnt vmcnt(0)" ::: "memory");
    __builtin_amdgcn_sched_barrier(0);

    // ---- PV
    f32x16 o;
#pragma unroll
    for (int e = 0; e < 16; ++e) o[e] = 0.f;

#pragma unroll
    for (int s = 0; s < 8; ++s) {
        f16x8 pa;
#pragma unroll
        for (int e = 0; e < 8; ++e) pa[e] = (f16)(p4[s >> 1][8 * (s & 1) + e]);
        f16x4 v0 = *reinterpret_cast<const f16x4*>(&Vw[(2 * s) * 256 + l31 * 8 + 4 * hi]);
        f16x4 v1 = *reinterpret_cast<const f16x4*>(&Vw[(2 * s + 1) * 256 + l31 * 8 + 4 * hi]);
        o = MFMA(pa, mk8(v0, v1), o);
    }

    // ---- O tile -> swizzled LDS (granule G = (col>>3) ^ (row&7))
    {
        const int col = h * 32 + l31;
        const int cg  = col >> 3;
        const int c7  = col & 7;
#pragma unroll
        for (int r = 0; r < 16; ++r) {
            int row = (r & 3) + 8 * (r >> 2) + 4 * hi;
            AOs[row * 256 + ((cg ^ (row & 7)) << 3) + c7] = (f16)o[r];
        }
    }
    __syncthreads();

    // ---- OUT[:, 32h..32h+31] = AO x Wo  (A from LDS, B from global Wsw[3])
    {
        const int xr = l31 & 7;
        const f16* Wb = Wsw + 3 * 65536 + (size_t)(h * 32 + l31) * 256;
        f32x16 acc;
#pragma unroll
        for (int e = 0; e < 16; ++e) acc[e] = 0.f;
#pragma unroll
        for (int g = 0; g < 16; ++g) {
            int gp = (2 * g + hi) ^ xr;
            f16x8 av = *(const f16x8*)&AOs[l31 * 256 + (gp << 3)];
            f16x8 bv = *(const f16x8*)(Wb + (gp << 3));
            acc = MFMA(av, bv, acc);
        }
#pragma unroll
        for (int r = 0; r < 16; ++r) {
            int row = (r & 3) + 8 * (r >> 2) + 4 * hi;
            OUT[((size_t)b * Mg + 32 * c + row) * 256 + h * 32 + l31] = (f16)acc[r];
        }
    }
}

// ---------------------------------------------------------------------------
// k_seg: segment mean per (token, batch). grid (2048, 2), block 256.
// (ref: out*=mask, then segment-sum weighted by mask -> msk^2 on OUT)
// ---------------------------------------------------------------------------
__global__ __launch_bounds__(256) void k_seg(const f16* __restrict__ OUT,
                                             const int* __restrict__ uid,
                                             const float* __restrict__ mask,
                                             float* __restrict__ out) {
    const int t = blockIdx.x, b = blockIdx.y;
    const int d = threadIdx.x;
    const int* u = uid + b * Mg;

    int lo = 0, hi = Mg;
    while (lo < hi) { int mid = (lo + hi) >> 1; if (u[mid] < t) lo = mid + 1; else hi = mid; }
    int lo2 = lo, hi2 = Mg;
    while (lo2 < hi2) { int mid = (lo2 + hi2) >> 1; if (u[mid] < t + 1) lo2 = mid + 1; else hi2 = mid; }

    float sum = 0.f, cnt = 0.f;
    for (int m = lo; m < lo2; ++m) {
        float msk = mask[b * Mg + m];
        sum += msk * msk * (float)OUT[((size_t)b * Mg + m) * 256 + d];
        cnt += msk;
    }
    out[((size_t)b * Ntok + t) * 256 + d] = sum / (cnt + 1e-8f);
}

// ---------------------------------------------------------------------------
extern "C" void kernel_launch(void* const* d_in, const int* in_sizes, int n_in,
                              void* d_out, int out_size, void* d_ws, size_t ws_size,
                              hipStream_t stream) {
    const float* f_atom = (const float*)d_in[0];
    const float* amask  = (const float*)d_in[1];
    const float* Wq     = (const float*)d_in[2];
    const float* Wk     = (const float*)d_in[3];
    const float* Wv     = (const float*)d_in[4];
    const float* Wo     = (const float*)d_in[5];
    const int*   uid    = (const int*)d_in[6];

    const size_t HALF_WT  = 4 * 65536;
    const size_t HALF_MAT = (size_t)Bg * Mg * Dg;
    const size_t needed_bytes = (HALF_WT + 4 * HALF_MAT) * sizeof(f16);
    if (ws_size < needed_bytes) return;

    f16* Wsw  = (f16*)d_ws;
    f16* Qb   = Wsw + HALF_WT;
    f16* Kb   = Qb + HALF_MAT;
    f16* VTb  = Kb + HALF_MAT;
    f16* OUTb = VTb + HALF_MAT;

    k_wt  <<<dim3(1024), 256, 0, stream>>>(Wq, Wk, Wv, Wo, Wsw);
    k_qkv <<<dim3(512), 256, 0, stream>>>(f_atom, Wsw, Qb, Kb, VTb);
    k_attn<<<dim3(1024), 512, 0, stream>>>(Qb, Kb, VTb, Wsw, OUTb);
    k_seg <<<dim3(Ntok, Bg), 256, 0, stream>>>(OUTb, uid, amask, (float*)d_out);
}

// Round 8
// 78.721 us; speedup vs baseline: 1.7266x; 1.1223x over previous
//
#include <hip/hip_runtime.h>

typedef _Float16 f16;
typedef _Float16 f16x4 __attribute__((ext_vector_type(4)));
typedef _Float16 f16x8 __attribute__((ext_vector_type(8)));
typedef float    f32x16 __attribute__((ext_vector_type(16)));

#define MFMA(a, b, c) __builtin_amdgcn_mfma_f32_32x32x16_f16((a), (b), (c), 0, 0, 0)

static constexpr int Mg   = 16384;
static constexpr int Bg   = 2;
static constexpr int Dg   = 256;
static constexpr int Hg   = 8;
static constexpr int Cg   = 512;
static constexpr int Ntok = 2048;
static constexpr float QSCALE = 0.17677669529663687f; // 1/sqrt(32)

typedef __attribute__((address_space(1))) const void gbl_cv;
typedef __attribute__((address_space(3))) void lds_v;

static __device__ __forceinline__ void gll16(const f16* g, f16* l) {
    __builtin_amdgcn_global_load_lds((gbl_cv*)g, (lds_v*)l, 16, 0, 0);
}
static __device__ __forceinline__ f16x8 mk8(f16x4 a, f16x4 b) {
    f16x8 r;
    r[0] = a[0]; r[1] = a[1]; r[2] = a[2]; r[3] = a[3];
    r[4] = b[0]; r[5] = b[1]; r[6] = b[2]; r[7] = b[3];
    return r;
}

// ---------------------------------------------------------------------------
// k_wt: W[k][n] fp32 -> fp16.
//   w<3 (Wq,Wk,Wv):  Wsw[w][n][granule (k>>3)^(n&7)]  (k_qkv staging layout)
//   w==3 (Wo):       Wsw[3][(k>>3)][n][k&7]           (granule-major, coalesced
//                    B-reads in k_attn phase 2)
// ---------------------------------------------------------------------------
__global__ __launch_bounds__(256) void k_wt(const float* __restrict__ Wq,
                                            const float* __restrict__ Wk,
                                            const float* __restrict__ Wv,
                                            const float* __restrict__ Wo,
                                            f16* __restrict__ Wsw) {
    int idx = blockIdx.x * 256 + threadIdx.x;
    int w   = idx >> 16;
    int rem = idx & 65535;
    int k   = rem >> 8;
    int n   = rem & 255;
    if (w < 3) {
        const float* W = (w == 0) ? Wq : (w == 1) ? Wk : Wv;
        int G = (k >> 3) ^ (n & 7);
        Wsw[w * 65536 + n * 256 + (G << 3) + (k & 7)] = (f16)W[k * 256 + n];
    } else {
        Wsw[3 * 65536 + ((k >> 3) * 256 + n) * 8 + (k & 7)] = (f16)Wo[k * 256 + n];
    }
}

// ---------------------------------------------------------------------------
// k_qkv: A-in-registers GEMM (validated R6). 512 blocks, 4 waves, 12 steps.
// V epilogue now writes granule-major VW[b][m>>3][d][m&7] (half-wave
// contiguous 512B stores).
// ---------------------------------------------------------------------------
__global__ __launch_bounds__(256, 2) void k_qkv(const float* __restrict__ A,
                                                const f16* __restrict__ Wsw,
                                                f16* __restrict__ Qo,
                                                f16* __restrict__ Ko,
                                                f16* __restrict__ VW) {
    __shared__ f16 Ls[2][32 * 256];   // 2 x 16 KB

    const int tid  = threadIdx.x;
    const int d    = blockIdx.x;
    const int lin  = (d & 7) * 64 + (d >> 3);
    const int yt   = lin >> 1;
    const int half = lin & 1;
    const int m0   = yt * 128;
    const int lane = tid & 63, w = tid >> 6;
    const int l31  = lane & 31, hi = lane >> 5;
    const int mrow = m0 + 32 * w + l31;
    const int xr   = l31 & 7;

    f16x8 a[16];
    const float* ap = A + (size_t)mrow * 256 + 8 * hi;
#pragma unroll
    for (int g = 0; g < 16; ++g) {
        float4 v0 = *reinterpret_cast<const float4*>(ap + 16 * g);
        float4 v1 = *reinterpret_cast<const float4*>(ap + 16 * g + 4);
        f16x8 t;
        t[0] = (f16)v0.x; t[1] = (f16)v0.y; t[2] = (f16)v0.z; t[3] = (f16)v0.w;
        t[4] = (f16)v1.x; t[5] = (f16)v1.y; t[6] = (f16)v1.z; t[7] = (f16)v1.w;
        a[g] = t;
    }

#define STW(S, BB)                                                             \
    {                                                                          \
        const f16* src = Wsw + ((S) >> 3) * 65536 + (((S) & 7) * 32) * 256;    \
        _Pragma("unroll")                                                      \
        for (int i = 0; i < 4; ++i) {                                          \
            int g2 = i * 256 + tid;                                            \
            gll16(src + g2 * 8, &Ls[BB][g2 * 8]);                              \
        }                                                                      \
    }

#define QKV_STEP(S, BB)                                                        \
    {                                                                          \
        if ((S) + 1 < s_end) { STW((S) + 1, (BB) ^ 1); }                       \
        f32x16 acc;                                                            \
        _Pragma("unroll")                                                      \
        for (int e = 0; e < 16; ++e) acc[e] = 0.f;                             \
        _Pragma("unroll")                                                      \
        for (int g = 0; g < 16; ++g) {                                         \
            f16x8 bf = *(const f16x8*)&Ls[BB][l31 * 256 +                      \
                                             (((2 * g + hi) ^ xr) << 3)];      \
            acc = MFMA(a[g], bf, acc);                                         \
        }                                                                      \
        const int wix  = (S) >> 3;                                             \
        const int gcol = ((S) & 7) * 32 + l31;                                 \
        const int mb   = m0 + 32 * w + 4 * hi;                                 \
        if (wix == 0) {                                                        \
            _Pragma("unroll")                                                  \
            for (int r = 0; r < 16; ++r)                                       \
                Qo[(size_t)(mb + (r & 3) + 8 * (r >> 2)) * 256 + gcol] =       \
                    (f16)(acc[r] * QSCALE);                                    \
        } else if (wix == 1) {                                                 \
            _Pragma("unroll")                                                  \
            for (int r = 0; r < 16; ++r)                                       \
                Ko[(size_t)(mb + (r & 3) + 8 * (r >> 2)) * 256 + gcol] =       \
                    (f16)acc[r];                                               \
        } else {                                                               \
            _Pragma("unroll")                                                  \
            for (int rq = 0; rq < 4; ++rq) {                                   \
                f16x4 pv = { (f16)acc[rq * 4 + 0], (f16)acc[rq * 4 + 1],       \
                             (f16)acc[rq * 4 + 2], (f16)acc[rq * 4 + 3] };     \
                int mr  = mb + 8 * rq;                                         \
                int bb2 = mr >> 14;                                            \
                int msg = (mr & 16383) >> 3;                                   \
                *reinterpret_cast<f16x4*>(VW + ((size_t)(bb2 * 2048 + msg) *   \
                                          256 + gcol) * 8 + 4 * hi) = pv;      \
            }                                                                  \
        }                                                                      \
        if ((S) + 1 < s_end) {                                                 \
            if (((S) >> 3) == 2) {                                             \
                asm volatile("s_waitcnt vmcnt(4)" ::: "memory");               \
            } else {                                                           \
                asm volatile("s_waitcnt vmcnt(16)" ::: "memory");              \
            }                                                                  \
            __builtin_amdgcn_s_barrier();                                      \
            __builtin_amdgcn_sched_barrier(0);                                 \
        }                                                                      \
    }

#define QKV_RUN(BASE)                                                          \
    {                                                                          \
        const int s_end = (BASE) + 12;                                         \
        STW(BASE, 0);                                                          \
        asm volatile("s_waitcnt vmcnt(0)" ::: "memory");                       \
        __builtin_amdgcn_s_barrier();                                          \
        __builtin_amdgcn_sched_barrier(0);                                     \
        _Pragma("unroll")                                                      \
        for (int ss = 0; ss < 12; ++ss) { QKV_STEP((BASE) + ss, ss & 1); }     \
    }

    if (half == 0) { QKV_RUN(0); } else { QKV_RUN(12); }
#undef QKV_RUN
#undef QKV_STEP
#undef STW
}

// ---------------------------------------------------------------------------
// k_attn v5 (fused, fully-coalesced). One 512-thr block per (b,c); wave = head.
//  - K window (128x256) + Q tile (32x256) block-staged via coalesced gll16,
//    row-key XOR swizzle; fragments via ds_read_b128 (<=4-way conflicts).
//  - V read direct to registers from granule-major VW (512B-contiguous spans),
//    issued before softmax.
//  - AOs (32 x 264, +8 pad) OVERLAYS K's LDS after QK^T; phase 2 reads A from
//    LDS, B coalesced from granule-major Wo slab.
// LDS = 64 + 16 KB = 80 KB -> 2 blocks/CU.
// ---------------------------------------------------------------------------
__global__ __launch_bounds__(512, 2) void k_attn(const f16* __restrict__ Qo,
                                                 const f16* __restrict__ Ko,
                                                 const f16* __restrict__ VW,
                                                 const f16* __restrict__ Wsw,
                                                 f16* __restrict__ OUT) {
    __shared__ f16 Ks[128 * 256];   // 64 KB (AOs overlays first 16.5 KB later)
    __shared__ f16 Qs[32 * 256];    // 16 KB

    const int tid  = threadIdx.x;
    const int idx  = blockIdx.x;
    const int lin  = (idx & 7) * 128 + (idx >> 3);   // contiguous (b,c) per XCD
    const int b    = lin >> 9;
    const int c    = lin & 511;
    const int h    = tid >> 6;
    const int l31  = tid & 31;
    const int hi   = (tid & 63) >> 5;

    const int u0 = 32 * c - 48;
    const int e0 = (32 * c + 80 < Mg) ? (32 * c + 80) : Mg;

    // ---- stage K window: 8 coalesced gll16 / thread
    const f16* Kb = Ko + (size_t)b * Mg * 256;
#pragma unroll
    for (int i = 0; i < 8; ++i) {
        int g = i * 512 + tid;
        int r = g >> 5, s = g & 31;
        int m = u0 + r;
        m = m < 0 ? 0 : (m > Mg - 1 ? Mg - 1 : m);
        gll16(Kb + (size_t)m * 256 + ((s ^ (r & 31)) << 3), &Ks[g * 8]);
    }
    // ---- stage Q tile: 2 coalesced gll16 / thread
    const f16* Qb = Qo + ((size_t)b * Mg + 32 * c) * 256;
#pragma unroll
    for (int i = 0; i < 2; ++i) {
        int g = i * 512 + tid;
        int r = g >> 5, s = g & 31;
        gll16(Qb + (size_t)r * 256 + ((s ^ r) << 3), &Qs[g * 8]);
    }
    __syncthreads();

    // ---- Q fragments from LDS (key = row = l31)
    f16x8 qf0 = *(const f16x8*)&Qs[l31 * 256 + (((4 * h + hi) ^ l31) << 3)];
    f16x8 qf1 = *(const f16x8*)&Qs[l31 * 256 + (((4 * h + 2 + hi) ^ l31) << 3)];

    // ---- QK^T from LDS
    f32x16 p4[4];
#pragma unroll
    for (int t = 0; t < 4; ++t)
#pragma unroll
        for (int e = 0; e < 16; ++e) p4[t][e] = 0.f;

#pragma unroll
    for (int t = 0; t < 4; ++t) {
        int rr = 32 * t + l31;
        f16x8 kf0 = *(const f16x8*)&Ks[rr * 256 + (((4 * h + hi) ^ l31) << 3)];
        f16x8 kf1 = *(const f16x8*)&Ks[rr * 256 + (((4 * h + 2 + hi) ^ l31) << 3)];
        p4[t] = MFMA(kf0, qf0, p4[t]);
        p4[t] = MFMA(kf1, qf1, p4[t]);
    }

    // ---- V loads direct to registers (coalesced 512B spans), before softmax
    const f16* Vbb = VW + (size_t)b * 2048 * 256 * 8;
    f16x4 v0r[8], v1r[8];
#pragma unroll
    for (int s = 0; s < 8; ++s) {
        int g0 = (u0 >> 3) + 2 * s;
        int g1 = g0 + 1;
        g0 = g0 < 0 ? 0 : (g0 > 2047 ? 2047 : g0);
        g1 = g1 < 0 ? 0 : (g1 > 2047 ? 2047 : g1);
        v0r[s] = *(const f16x4*)(Vbb + ((size_t)g0 * 256 + 32 * h + l31) * 8 + 4 * hi);
        v1r[s] = *(const f16x4*)(Vbb + ((size_t)g1 * 256 + 32 * h + l31) * 8 + 4 * hi);
    }

    // ---- masked in-register softmax (lane owns q-row l31; halves via lane^32)
    float mx = -3e38f;
#pragma unroll
    for (int t = 0; t < 4; ++t)
#pragma unroll
        for (int r = 0; r < 16; ++r) {
            int gm = u0 + 32 * t + (r & 3) + 8 * (r >> 2) + 4 * hi;
            if (gm >= 0 && gm < e0) mx = fmaxf(mx, p4[t][r]);
        }
    mx = fmaxf(mx, __shfl_xor(mx, 32));

    float sum = 0.f;
#pragma unroll
    for (int t = 0; t < 4; ++t)
#pragma unroll
        for (int r = 0; r < 16; ++r) {
            int gm = u0 + 32 * t + (r & 3) + 8 * (r >> 2) + 4 * hi;
            float ev = (gm >= 0 && gm < e0) ? __expf(p4[t][r] - mx) : 0.f;
            p4[t][r] = ev;
            sum += ev;
        }
    sum += __shfl_xor(sum, 32);
    const float inv = 1.f / sum;
#pragma unroll
    for (int t = 0; t < 4; ++t)
#pragma unroll
        for (int e = 0; e < 16; ++e) p4[t][e] *= inv;

    // ---- PV (all-register)
    f32x16 o;
#pragma unroll
    for (int e = 0; e < 16; ++e) o[e] = 0.f;

#pragma unroll
    for (int s = 0; s < 8; ++s) {
        f16x8 pa;
#pragma unroll
        for (int e = 0; e < 8; ++e) pa[e] = (f16)(p4[s >> 1][8 * (s & 1) + e]);
        o = MFMA(pa, mk8(v0r[s], v1r[s]), o);
    }

    // ---- AOs overlays K LDS (all QK^T reads are done after this barrier)
    __syncthreads();
    {
        const int col = h * 32 + l31;
#pragma unroll
        for (int r = 0; r < 16; ++r) {
            int row = (r & 3) + 8 * (r >> 2) + 4 * hi;
            Ks[row * 264 + col] = (f16)o[r];
        }
    }
    __syncthreads();

    // ---- phase 2: OUT[:, 32h..32h+31] = AO x Wo
    {
        const f16* Wb = Wsw + 3 * 65536;
        f32x16 acc;
#pragma unroll
        for (int e = 0; e < 16; ++e) acc[e] = 0.f;
#pragma unroll
        for (int g = 0; g < 16; ++g) {
            int gp = 2 * g + hi;
            f16x8 av = *(const f16x8*)&Ks[l31 * 264 + gp * 8];
            f16x8 bv = *(const f16x8*)(Wb + ((size_t)gp * 256 + 32 * h + l31) * 8);
            acc = MFMA(av, bv, acc);
        }
#pragma unroll
        for (int r = 0; r < 16; ++r) {
            int row = (r & 3) + 8 * (r >> 2) + 4 * hi;
            OUT[((size_t)b * Mg + 32 * c + row) * 256 + h * 32 + l31] = (f16)acc[r];
        }
    }
}

// ---------------------------------------------------------------------------
// k_seg: segment mean per (token, batch). grid (2048, 2), block 256.
// (ref: out*=mask, then segment-sum weighted by mask -> msk^2 on OUT)
// ---------------------------------------------------------------------------
__global__ __launch_bounds__(256) void k_seg(const f16* __restrict__ OUT,
                                             const int* __restrict__ uid,
                                             const float* __restrict__ mask,
                                             float* __restrict__ out) {
    const int t = blockIdx.x, b = blockIdx.y;
    const int d = threadIdx.x;
    const int* u = uid + b * Mg;

    int lo = 0, hi = Mg;
    while (lo < hi) { int mid = (lo + hi) >> 1; if (u[mid] < t) lo = mid + 1; else hi = mid; }
    int lo2 = lo, hi2 = Mg;
    while (lo2 < hi2) { int mid = (lo2 + hi2) >> 1; if (u[mid] < t + 1) lo2 = mid + 1; else hi2 = mid; }

    float sum = 0.f, cnt = 0.f;
    for (int m = lo; m < lo2; ++m) {
        float msk = mask[b * Mg + m];
        sum += msk * msk * (float)OUT[((size_t)b * Mg + m) * 256 + d];
        cnt += msk;
    }
    out[((size_t)b * Ntok + t) * 256 + d] = sum / (cnt + 1e-8f);
}

// ---------------------------------------------------------------------------
extern "C" void kernel_launch(void* const* d_in, const int* in_sizes, int n_in,
                              void* d_out, int out_size, void* d_ws, size_t ws_size,
                              hipStream_t stream) {
    const float* f_atom = (const float*)d_in[0];
    const float* amask  = (const float*)d_in[1];
    const float* Wq     = (const float*)d_in[2];
    const float* Wk     = (const float*)d_in[3];
    const float* Wv     = (const float*)d_in[4];
    const float* Wo     = (const float*)d_in[5];
    const int*   uid    = (const int*)d_in[6];

    const size_t HALF_WT  = 4 * 65536;
    const size_t HALF_MAT = (size_t)Bg * Mg * Dg;
    const size_t needed_bytes = (HALF_WT + 4 * HALF_MAT) * sizeof(f16);
    if (ws_size < needed_bytes) return;

    f16* Wsw  = (f16*)d_ws;
    f16* Qb   = Wsw + HALF_WT;
    f16* Kb   = Qb + HALF_MAT;
    f16* VWb  = Kb + HALF_MAT;
    f16* OUTb = VWb + HALF_MAT;

    k_wt  <<<dim3(1024), 256, 0, stream>>>(Wq, Wk, Wv, Wo, Wsw);
    k_qkv <<<dim3(512), 256, 0, stream>>>(f_atom, Wsw, Qb, Kb, VWb);
    k_attn<<<dim3(1024), 512, 0, stream>>>(Qb, Kb, VWb, Wsw, OUTb);
    k_seg <<<dim3(Ntok, Bg), 256, 0, stream>>>(OUTb, uid, amask, (float*)d_out);
}

// Round 9
// 72.995 us; speedup vs baseline: 1.8620x; 1.0784x over previous
//
#include <hip/hip_runtime.h>

typedef _Float16 f16;
typedef _Float16 f16x4 __attribute__((ext_vector_type(4)));
typedef _Float16 f16x8 __attribute__((ext_vector_type(8)));
typedef float    f32x16 __attribute__((ext_vector_type(16)));

#define MFMA(a, b, c) __builtin_amdgcn_mfma_f32_32x32x16_f16((a), (b), (c), 0, 0, 0)

static constexpr int Mg   = 16384;
static constexpr int Bg   = 2;
static constexpr int Dg   = 256;
static constexpr int Hg   = 8;
static constexpr int Cg   = 512;
static constexpr int Ntok = 2048;
static constexpr float QSCALE = 0.17677669529663687f; // 1/sqrt(32)

typedef __attribute__((address_space(1))) const void gbl_cv;
typedef __attribute__((address_space(3))) void lds_v;

static __device__ __forceinline__ void gll16(const f16* g, f16* l) {
    __builtin_amdgcn_global_load_lds((gbl_cv*)g, (lds_v*)l, 16, 0, 0);
}
static __device__ __forceinline__ f16x8 mk8(f16x4 a, f16x4 b) {
    f16x8 r;
    r[0] = a[0]; r[1] = a[1]; r[2] = a[2]; r[3] = a[3];
    r[4] = b[0]; r[5] = b[1]; r[6] = b[2]; r[7] = b[3];
    return r;
}

// ---------------------------------------------------------------------------
// k_wt: W[k][n] fp32 -> fp16 slabs (unchanged layouts), plus: first 4098
// threads ALSO binary-search token boundaries into starts[b][t] for k_seg.
// ---------------------------------------------------------------------------
__global__ __launch_bounds__(256) void k_wt(const float* __restrict__ Wq,
                                            const float* __restrict__ Wk,
                                            const float* __restrict__ Wv,
                                            const float* __restrict__ Wo,
                                            const int* __restrict__ uid,
                                            f16* __restrict__ Wsw,
                                            int* __restrict__ starts) {
    int idx = blockIdx.x * 256 + threadIdx.x;
    int w   = idx >> 16;
    int rem = idx & 65535;
    int k   = rem >> 8;
    int n   = rem & 255;
    if (w < 3) {
        const float* W = (w == 0) ? Wq : (w == 1) ? Wk : Wv;
        int G = (k >> 3) ^ (n & 7);
        Wsw[w * 65536 + n * 256 + (G << 3) + (k & 7)] = (f16)W[k * 256 + n];
    } else {
        Wsw[3 * 65536 + ((k >> 3) * 256 + n) * 8 + (k & 7)] = (f16)Wo[k * 256 + n];
    }
    if (idx < 2 * 2049) {
        int b = idx / 2049, t = idx % 2049;
        const int* u = uid + b * Mg;
        int lo = 0, hi = Mg;
        while (lo < hi) { int mid = (lo + hi) >> 1; if (u[mid] < t) lo = mid + 1; else hi = mid; }
        starts[idx] = lo;
    }
}

// ---------------------------------------------------------------------------
// k_qkv: A-in-registers GEMM (validated R6/R8). 512 blocks, 4 waves, 12 steps.
// First W-tile stage issued BEFORE the A-register loads (latency overlap).
// V written granule-major VW[b][m>>3][d][m&7].
// ---------------------------------------------------------------------------
__global__ __launch_bounds__(256, 2) void k_qkv(const float* __restrict__ A,
                                                const f16* __restrict__ Wsw,
                                                f16* __restrict__ Qo,
                                                f16* __restrict__ Ko,
                                                f16* __restrict__ VW) {
    __shared__ f16 Ls[2][32 * 256];   // 2 x 16 KB

    const int tid  = threadIdx.x;
    const int d    = blockIdx.x;
    const int lin  = (d & 7) * 64 + (d >> 3);
    const int yt   = lin >> 1;
    const int half = lin & 1;
    const int m0   = yt * 128;
    const int lane = tid & 63, w = tid >> 6;
    const int l31  = lane & 31, hi = lane >> 5;
    const int mrow = m0 + 32 * w + l31;
    const int xr   = l31 & 7;

#define STW(S, BB)                                                             \
    {                                                                          \
        const f16* src = Wsw + ((S) >> 3) * 65536 + (((S) & 7) * 32) * 256;    \
        _Pragma("unroll")                                                      \
        for (int i = 0; i < 4; ++i) {                                          \
            int g2 = i * 256 + tid;                                            \
            gll16(src + g2 * 8, &Ls[BB][g2 * 8]);                              \
        }                                                                      \
    }

    // ---- issue first W stage, then A loads (stage latency hides under A)
    if (half == 0) { STW(0, 0); } else { STW(12, 0); }

    f16x8 a[16];
    const float* ap = A + (size_t)mrow * 256 + 8 * hi;
#pragma unroll
    for (int g = 0; g < 16; ++g) {
        float4 v0 = *reinterpret_cast<const float4*>(ap + 16 * g);
        float4 v1 = *reinterpret_cast<const float4*>(ap + 16 * g + 4);
        f16x8 t;
        t[0] = (f16)v0.x; t[1] = (f16)v0.y; t[2] = (f16)v0.z; t[3] = (f16)v0.w;
        t[4] = (f16)v1.x; t[5] = (f16)v1.y; t[6] = (f16)v1.z; t[7] = (f16)v1.w;
        a[g] = t;
    }

#define QKV_STEP(S, BB)                                                        \
    {                                                                          \
        if ((S) + 1 < s_end) { STW((S) + 1, (BB) ^ 1); }                       \
        f32x16 acc;                                                            \
        _Pragma("unroll")                                                      \
        for (int e = 0; e < 16; ++e) acc[e] = 0.f;                             \
        _Pragma("unroll")                                                      \
        for (int g = 0; g < 16; ++g) {                                         \
            f16x8 bf = *(const f16x8*)&Ls[BB][l31 * 256 +                      \
                                             (((2 * g + hi) ^ xr) << 3)];      \
            acc = MFMA(a[g], bf, acc);                                         \
        }                                                                      \
        const int wix  = (S) >> 3;                                             \
        const int gcol = ((S) & 7) * 32 + l31;                                 \
        const int mb   = m0 + 32 * w + 4 * hi;                                 \
        if (wix == 0) {                                                        \
            _Pragma("unroll")                                                  \
            for (int r = 0; r < 16; ++r)                                       \
                Qo[(size_t)(mb + (r & 3) + 8 * (r >> 2)) * 256 + gcol] =       \
                    (f16)(acc[r] * QSCALE);                                    \
        } else if (wix == 1) {                                                 \
            _Pragma("unroll")                                                  \
            for (int r = 0; r < 16; ++r)                                       \
                Ko[(size_t)(mb + (r & 3) + 8 * (r >> 2)) * 256 + gcol] =       \
                    (f16)acc[r];                                               \
        } else {                                                               \
            _Pragma("unroll")                                                  \
            for (int rq = 0; rq < 4; ++rq) {                                   \
                f16x4 pv = { (f16)acc[rq * 4 + 0], (f16)acc[rq * 4 + 1],       \
                             (f16)acc[rq * 4 + 2], (f16)acc[rq * 4 + 3] };     \
                int mr  = mb + 8 * rq;                                         \
                int bb2 = mr >> 14;                                            \
                int msg = (mr & 16383) >> 3;                                   \
                *reinterpret_cast<f16x4*>(VW + ((size_t)(bb2 * 2048 + msg) *   \
                                          256 + gcol) * 8 + 4 * hi) = pv;      \
            }                                                                  \
        }                                                                      \
        if ((S) + 1 < s_end) {                                                 \
            if (((S) >> 3) == 2) {                                             \
                asm volatile("s_waitcnt vmcnt(4)" ::: "memory");               \
            } else {                                                           \
                asm volatile("s_waitcnt vmcnt(16)" ::: "memory");              \
            }                                                                  \
            __builtin_amdgcn_s_barrier();                                      \
            __builtin_amdgcn_sched_barrier(0);                                 \
        }                                                                      \
    }

#define QKV_RUN(BASE)                                                          \
    {                                                                          \
        const int s_end = (BASE) + 12;                                         \
        asm volatile("s_waitcnt vmcnt(0)" ::: "memory");                       \
        __builtin_amdgcn_s_barrier();                                          \
        __builtin_amdgcn_sched_barrier(0);                                     \
        _Pragma("unroll")                                                      \
        for (int ss = 0; ss < 12; ++ss) { QKV_STEP((BASE) + ss, ss & 1); }     \
    }

    if (half == 0) { QKV_RUN(0); } else { QKV_RUN(12); }
#undef QKV_RUN
#undef QKV_STEP
#undef STW
}

// ---------------------------------------------------------------------------
// k_attn (fused attn + Wo proj, R8 structure). Changes: V reg-loads hoisted
// right after the staging barrier; block-uniform fast-path softmax for the
// 508/512 full-window blocks; s_setprio(1) around MFMA clusters.
// LDS 80 KB -> 2 blocks/CU; launch_bounds(512,2) (no VGPR spill).
// ---------------------------------------------------------------------------
__global__ __launch_bounds__(512, 2) void k_attn(const f16* __restrict__ Qo,
                                                 const f16* __restrict__ Ko,
                                                 const f16* __restrict__ VW,
                                                 const f16* __restrict__ Wsw,
                                                 f16* __restrict__ OUT) {
    __shared__ f16 Ks[128 * 256];   // 64 KB (AOs overlays part of it later)
    __shared__ f16 Qs[32 * 256];    // 16 KB

    const int tid  = threadIdx.x;
    const int idx  = blockIdx.x;
    const int lin  = (idx & 7) * 128 + (idx >> 3);   // contiguous (b,c) per XCD
    const int b    = lin >> 9;
    const int c    = lin & 511;
    const int h    = tid >> 6;
    const int l31  = tid & 31;
    const int hi   = (tid & 63) >> 5;

    const int u0 = 32 * c - 48;
    const int e0 = (32 * c + 80 < Mg) ? (32 * c + 80) : Mg;
    const bool full = (u0 >= 0) && (32 * c + 80 <= Mg);

    // ---- stage K window: 8 coalesced gll16 / thread
    const f16* Kb = Ko + (size_t)b * Mg * 256;
#pragma unroll
    for (int i = 0; i < 8; ++i) {
        int g = i * 512 + tid;
        int r = g >> 5, s = g & 31;
        int m = u0 + r;
        m = m < 0 ? 0 : (m > Mg - 1 ? Mg - 1 : m);
        gll16(Kb + (size_t)m * 256 + ((s ^ (r & 31)) << 3), &Ks[g * 8]);
    }
    // ---- stage Q tile: 2 coalesced gll16 / thread
    const f16* Qb = Qo + ((size_t)b * Mg + 32 * c) * 256;
#pragma unroll
    for (int i = 0; i < 2; ++i) {
        int g = i * 512 + tid;
        int r = g >> 5, s = g & 31;
        gll16(Qb + (size_t)r * 256 + ((s ^ r) << 3), &Qs[g * 8]);
    }
    __syncthreads();

    // ---- V loads direct to registers, issued early (hidden under QK^T+softmax)
    const f16* Vbb = VW + (size_t)b * 2048 * 256 * 8;
    f16x4 v0r[8], v1r[8];
#pragma unroll
    for (int s = 0; s < 8; ++s) {
        int g0 = (u0 >> 3) + 2 * s;
        int g1 = g0 + 1;
        g0 = g0 < 0 ? 0 : (g0 > 2047 ? 2047 : g0);
        g1 = g1 < 0 ? 0 : (g1 > 2047 ? 2047 : g1);
        v0r[s] = *(const f16x4*)(Vbb + ((size_t)g0 * 256 + 32 * h + l31) * 8 + 4 * hi);
        v1r[s] = *(const f16x4*)(Vbb + ((size_t)g1 * 256 + 32 * h + l31) * 8 + 4 * hi);
    }

    // ---- Q fragments from LDS (key = row = l31)
    f16x8 qf0 = *(const f16x8*)&Qs[l31 * 256 + (((4 * h + hi) ^ l31) << 3)];
    f16x8 qf1 = *(const f16x8*)&Qs[l31 * 256 + (((4 * h + 2 + hi) ^ l31) << 3)];

    // ---- QK^T from LDS
    f32x16 p4[4];
#pragma unroll
    for (int t = 0; t < 4; ++t)
#pragma unroll
        for (int e = 0; e < 16; ++e) p4[t][e] = 0.f;

    __builtin_amdgcn_s_setprio(1);
#pragma unroll
    for (int t = 0; t < 4; ++t) {
        int rr = 32 * t + l31;
        f16x8 kf0 = *(const f16x8*)&Ks[rr * 256 + (((4 * h + hi) ^ l31) << 3)];
        f16x8 kf1 = *(const f16x8*)&Ks[rr * 256 + (((4 * h + 2 + hi) ^ l31) << 3)];
        p4[t] = MFMA(kf0, qf0, p4[t]);
        p4[t] = MFMA(kf1, qf1, p4[t]);
    }
    __builtin_amdgcn_s_setprio(0);

    // ---- in-register softmax (lane owns q-row l31; halves via lane^32)
    float mx = -3e38f;
    float sum = 0.f;
    if (full) {
#pragma unroll
        for (int t = 0; t < 4; ++t)
#pragma unroll
            for (int r = 0; r < 16; ++r) mx = fmaxf(mx, p4[t][r]);
        mx = fmaxf(mx, __shfl_xor(mx, 32));
#pragma unroll
        for (int t = 0; t < 4; ++t)
#pragma unroll
            for (int r = 0; r < 16; ++r) {
                float ev = __expf(p4[t][r] - mx);
                p4[t][r] = ev;
                sum += ev;
            }
    } else {
#pragma unroll
        for (int t = 0; t < 4; ++t)
#pragma unroll
            for (int r = 0; r < 16; ++r) {
                int gm = u0 + 32 * t + (r & 3) + 8 * (r >> 2) + 4 * hi;
                if (gm >= 0 && gm < e0) mx = fmaxf(mx, p4[t][r]);
            }
        mx = fmaxf(mx, __shfl_xor(mx, 32));
#pragma unroll
        for (int t = 0; t < 4; ++t)
#pragma unroll
            for (int r = 0; r < 16; ++r) {
                int gm = u0 + 32 * t + (r & 3) + 8 * (r >> 2) + 4 * hi;
                float ev = (gm >= 0 && gm < e0) ? __expf(p4[t][r] - mx) : 0.f;
                p4[t][r] = ev;
                sum += ev;
            }
    }
    sum += __shfl_xor(sum, 32);
    const float inv = 1.f / sum;
#pragma unroll
    for (int t = 0; t < 4; ++t)
#pragma unroll
        for (int e = 0; e < 16; ++e) p4[t][e] *= inv;

    // ---- PV (all-register; V loads drained here)
    asm volatile("s_waitcnt vmcnt(0)" ::: "memory");
    __builtin_amdgcn_sched_barrier(0);

    f32x16 o;
#pragma unroll
    for (int e = 0; e < 16; ++e) o[e] = 0.f;

    __builtin_amdgcn_s_setprio(1);
#pragma unroll
    for (int s = 0; s < 8; ++s) {
        f16x8 pa;
#pragma unroll
        for (int e = 0; e < 8; ++e) pa[e] = (f16)(p4[s >> 1][8 * (s & 1) + e]);
        o = MFMA(pa, mk8(v0r[s], v1r[s]), o);
    }
    __builtin_amdgcn_s_setprio(0);

    // ---- AOs overlays K LDS (QK^T reads done after this barrier)
    __syncthreads();
    {
        const int col = h * 32 + l31;
#pragma unroll
        for (int r = 0; r < 16; ++r) {
            int row = (r & 3) + 8 * (r >> 2) + 4 * hi;
            Ks[row * 264 + col] = (f16)o[r];
        }
    }
    __syncthreads();

    // ---- phase 2: OUT[:, 32h..32h+31] = AO x Wo
    {
        const f16* Wb = Wsw + 3 * 65536;
        f32x16 acc;
#pragma unroll
        for (int e = 0; e < 16; ++e) acc[e] = 0.f;
        __builtin_amdgcn_s_setprio(1);
#pragma unroll
        for (int g = 0; g < 16; ++g) {
            int gp = 2 * g + hi;
            f16x8 av = *(const f16x8*)&Ks[l31 * 264 + gp * 8];
            f16x8 bv = *(const f16x8*)(Wb + ((size_t)gp * 256 + 32 * h + l31) * 8);
            acc = MFMA(av, bv, acc);
        }
        __builtin_amdgcn_s_setprio(0);
#pragma unroll
        for (int r = 0; r < 16; ++r) {
            int row = (r & 3) + 8 * (r >> 2) + 4 * hi;
            OUT[((size_t)b * Mg + 32 * c + row) * 256 + h * 32 + l31] = (f16)acc[r];
        }
    }
}

// ---------------------------------------------------------------------------
// k_seg: segment mean per (token, batch), boundaries precomputed in k_wt.
// grid (2048, 2), block 256. (ref applies mask twice -> msk^2 weighting)
// ---------------------------------------------------------------------------
__global__ __launch_bounds__(256) void k_seg(const f16* __restrict__ OUT,
                                             const int* __restrict__ starts,
                                             const float* __restrict__ mask,
                                             float* __restrict__ out) {
    const int t = blockIdx.x, b = blockIdx.y;
    const int d = threadIdx.x;

    const int lo  = starts[b * 2049 + t];
    const int lo2 = starts[b * 2049 + t + 1];

    float sum = 0.f, cnt = 0.f;
    for (int m = lo; m < lo2; ++m) {
        float msk = mask[b * Mg + m];
        sum += msk * msk * (float)OUT[((size_t)b * Mg + m) * 256 + d];
        cnt += msk;
    }
    out[((size_t)b * Ntok + t) * 256 + d] = sum / (cnt + 1e-8f);
}

// ---------------------------------------------------------------------------
extern "C" void kernel_launch(void* const* d_in, const int* in_sizes, int n_in,
                              void* d_out, int out_size, void* d_ws, size_t ws_size,
                              hipStream_t stream) {
    const float* f_atom = (const float*)d_in[0];
    const float* amask  = (const float*)d_in[1];
    const float* Wq     = (const float*)d_in[2];
    const float* Wk     = (const float*)d_in[3];
    const float* Wv     = (const float*)d_in[4];
    const float* Wo     = (const float*)d_in[5];
    const int*   uid    = (const int*)d_in[6];

    const size_t HALF_WT  = 4 * 65536;
    const size_t HALF_MAT = (size_t)Bg * Mg * Dg;
    const size_t needed_bytes = (HALF_WT + 4 * HALF_MAT) * sizeof(f16) + 2 * 2049 * sizeof(int);
    if (ws_size < needed_bytes) return;

    f16* Wsw  = (f16*)d_ws;
    f16* Qb   = Wsw + HALF_WT;
    f16* Kb   = Qb + HALF_MAT;
    f16* VWb  = Kb + HALF_MAT;
    f16* OUTb = VWb + HALF_MAT;
    int* starts = (int*)(OUTb + HALF_MAT);

    k_wt  <<<dim3(1024), 256, 0, stream>>>(Wq, Wk, Wv, Wo, uid, Wsw, starts);
    k_qkv <<<dim3(512), 256, 0, stream>>>(f_atom, Wsw, Qb, Kb, VWb);
    k_attn<<<dim3(1024), 512, 0, stream>>>(Qb, Kb, VWb, Wsw, OUTb);
    k_seg <<<dim3(Ntok, Bg), 256, 0, stream>>>(OUTb, starts, amask, (float*)d_out);
}